// Round 3
// baseline (3486.628 us; speedup 1.0000x reference)
//
#include <hip/hip_runtime.h>
#include <math.h>

constexpr int kN = 170000;
constexpr int kE = 2720000;
constexpr int kFin = 128;
constexpr int kFh = 256;
constexpr int kL = 4;
constexpr int kFout = 40;

__device__ __forceinline__ float jk_b2f(unsigned short u) {
    unsigned int x = ((unsigned int)u) << 16;
    float f;
    __builtin_memcpy(&f, &x, 4);
    return f;
}
__device__ __forceinline__ unsigned short jk_f2b(float f) {
    unsigned int x;
    __builtin_memcpy(&x, &f, 4);
    unsigned int r = (x + 0x7fffu + ((x >> 16) & 1u)) >> 16;
    return (unsigned short)r;
}

__global__ void jk2_zero_i(int* p, int n) {
    int i = blockIdx.x * blockDim.x + threadIdx.x;
    if (i < n) p[i] = 0;
}
__global__ void jk2_zero_f(float* p, int n) {
    int i = blockIdx.x * blockDim.x + threadIdx.x;
    if (i < n) p[i] = 0.0f;
}

// Detect int64-vs-int32 edge buffer: if int64, the high 32-bit word of every
// element is 0 (indices < 170000). flag[0]=shift (1 if int64 else 0), flag[1]=0.
__global__ void jk2_detect(const int* eb, int* flag) {
    __shared__ int nz;
    if (threadIdx.x == 0) nz = 0;
    __syncthreads();
    int bad = 0;
    for (int j = 0; j < 4; j++) {
        int idx = threadIdx.x * 4 + j;
        if (eb[2 * idx + 1] != 0) bad = 1;
    }
    if (bad) atomicOr(&nz, 1);
    __syncthreads();
    if (threadIdx.x == 0) {
        flag[0] = nz ? 0 : 1;
        flag[1] = 0;
    }
}

__global__ void jk2_count(const int* eb, const int* flag, int* counts) {
    int s64 = flag[0];
    for (int e = blockIdx.x * blockDim.x + threadIdx.x; e < kE; e += gridDim.x * blockDim.x) {
        int d = eb[(kE + e) << s64];
        atomicAdd(&counts[d], 1);
    }
}

__global__ void jk2_nodeprep(const int* counts, float* dinv, float* invdeg, int* off, int* pos,
                             int* cursor) {
    int n = blockIdx.x * blockDim.x + threadIdx.x;
    if (n < kN) {
        int c = counts[n];
        float deg = (float)c + 1.0f;
        dinv[n] = rsqrtf(deg);
        invdeg[n] = 1.0f / deg;
        int o = atomicAdd(cursor, c);
        off[n] = o;
        pos[n] = o;
    }
}

__global__ void jk2_fill(const int* eb, const int* flag, const float* dinv, int* pos,
                         int* csr_src, float* csr_w) {
    int s64 = flag[0];
    for (int e = blockIdx.x * blockDim.x + threadIdx.x; e < kE; e += gridDim.x * blockDim.x) {
        int s = eb[e << s64];
        int d = eb[(kE + e) << s64];
        float w = dinv[s] * dinv[d];
        int p = atomicAdd(&pos[d], 1);
        csr_src[p] = s;
        csr_w[p] = w;
    }
}

// C[bf16, kN x 256] = A[fp32, kN x 128] @ W[128 x 256]
__global__ __launch_bounds__(256) void jk2_gemm_f32(const float* A, const float* W,
                                                    unsigned short* C) {
    __shared__ float As[128][33];
    __shared__ float Bs[32][64];
    int tid = threadIdx.x;
    int tx = tid & 15, ty = tid >> 4;
    int row0 = blockIdx.x * 128;
    int bn0 = blockIdx.y * 64;
    float acc[8][4] = {};
    for (int k0 = 0; k0 < kFin; k0 += 32) {
        for (int f = tid; f < 1024; f += 256) {
            int r = f >> 3, k4 = (f & 7) * 4;
            int row = row0 + r;
            float4 v = make_float4(0.f, 0.f, 0.f, 0.f);
            if (row < kN) v = *(const float4*)(A + (size_t)row * kFin + k0 + k4);
            As[r][k4 + 0] = v.x; As[r][k4 + 1] = v.y; As[r][k4 + 2] = v.z; As[r][k4 + 3] = v.w;
        }
        for (int f = tid; f < 512; f += 256) {
            int kk = f >> 4, c4 = (f & 15) * 4;
            float4 v = *(const float4*)(W + (size_t)(k0 + kk) * kFh + bn0 + c4);
            Bs[kk][c4 + 0] = v.x; Bs[kk][c4 + 1] = v.y; Bs[kk][c4 + 2] = v.z; Bs[kk][c4 + 3] = v.w;
        }
        __syncthreads();
#pragma unroll
        for (int kk = 0; kk < 32; kk++) {
            float b0 = Bs[kk][tx * 4 + 0], b1 = Bs[kk][tx * 4 + 1];
            float b2 = Bs[kk][tx * 4 + 2], b3 = Bs[kk][tx * 4 + 3];
#pragma unroll
            for (int i = 0; i < 8; i++) {
                float a = As[ty * 8 + i][kk];
                acc[i][0] += a * b0;
                acc[i][1] += a * b1;
                acc[i][2] += a * b2;
                acc[i][3] += a * b3;
            }
        }
        __syncthreads();
    }
#pragma unroll
    for (int i = 0; i < 8; i++) {
        int row = row0 + ty * 8 + i;
        if (row < kN) {
            ushort4 o;
            o.x = jk_f2b(acc[i][0]); o.y = jk_f2b(acc[i][1]);
            o.z = jk_f2b(acc[i][2]); o.w = jk_f2b(acc[i][3]);
            *(ushort4*)(C + (size_t)row * kFh + bn0 + tx * 4) = o;
        }
    }
}

// C[bf16, kN x 256] = A[bf16, kN x 256] @ W[256 x 256]
__global__ __launch_bounds__(256) void jk2_gemm_bf(const unsigned short* A, const float* W,
                                                   unsigned short* C) {
    __shared__ float As[128][33];
    __shared__ float Bs[32][64];
    int tid = threadIdx.x;
    int tx = tid & 15, ty = tid >> 4;
    int row0 = blockIdx.x * 128;
    int bn0 = blockIdx.y * 64;
    float acc[8][4] = {};
    for (int k0 = 0; k0 < kFh; k0 += 32) {
        for (int f = tid; f < 512; f += 256) {
            int r = f >> 2, k8 = (f & 3) * 8;
            int row = row0 + r;
            float v[8];
            if (row < kN) {
                ushort4 u0 = *(const ushort4*)(A + (size_t)row * kFh + k0 + k8);
                ushort4 u1 = *(const ushort4*)(A + (size_t)row * kFh + k0 + k8 + 4);
                v[0] = jk_b2f(u0.x); v[1] = jk_b2f(u0.y); v[2] = jk_b2f(u0.z); v[3] = jk_b2f(u0.w);
                v[4] = jk_b2f(u1.x); v[5] = jk_b2f(u1.y); v[6] = jk_b2f(u1.z); v[7] = jk_b2f(u1.w);
            } else {
                for (int j = 0; j < 8; j++) v[j] = 0.0f;
            }
            for (int j = 0; j < 8; j++) As[r][k8 + j] = v[j];
        }
        for (int f = tid; f < 512; f += 256) {
            int kk = f >> 4, c4 = (f & 15) * 4;
            float4 v = *(const float4*)(W + (size_t)(k0 + kk) * kFh + bn0 + c4);
            Bs[kk][c4 + 0] = v.x; Bs[kk][c4 + 1] = v.y; Bs[kk][c4 + 2] = v.z; Bs[kk][c4 + 3] = v.w;
        }
        __syncthreads();
#pragma unroll
        for (int kk = 0; kk < 32; kk++) {
            float b0 = Bs[kk][tx * 4 + 0], b1 = Bs[kk][tx * 4 + 1];
            float b2 = Bs[kk][tx * 4 + 2], b3 = Bs[kk][tx * 4 + 3];
#pragma unroll
            for (int i = 0; i < 8; i++) {
                float a = As[ty * 8 + i][kk];
                acc[i][0] += a * b0;
                acc[i][1] += a * b1;
                acc[i][2] += a * b2;
                acc[i][3] += a * b3;
            }
        }
        __syncthreads();
    }
#pragma unroll
    for (int i = 0; i < 8; i++) {
        int row = row0 + ty * 8 + i;
        if (row < kN) {
            ushort4 o;
            o.x = jk_f2b(acc[i][0]); o.y = jk_f2b(acc[i][1]);
            o.z = jk_f2b(acc[i][2]); o.w = jk_f2b(acc[i][3]);
            *(ushort4*)(C + (size_t)row * kFh + bn0 + tx * 4) = o;
        }
    }
}

// h[n,:] = sum_{e: dst=n} w_e * t[src_e,:] + t[n,:]*invdeg[n] + bias
__global__ __launch_bounds__(256) void jk2_agg(const unsigned short* t, const float* bias,
                                               const int* off, const int* cnt, const int* csr_src,
                                               const float* csr_w, const float* invdeg,
                                               unsigned short* h) {
    int wid = threadIdx.x >> 6;
    int lane = threadIdx.x & 63;
    int n = blockIdx.x * 4 + wid;
    if (n >= kN) return;
    int c0 = lane * 4;
    ushort4 u = *(const ushort4*)(t + (size_t)n * kFh + c0);
    float id = invdeg[n];
    float a0 = jk_b2f(u.x) * id, a1 = jk_b2f(u.y) * id;
    float a2 = jk_b2f(u.z) * id, a3 = jk_b2f(u.w) * id;
    int base = off[n], c = cnt[n];
    for (int i = 0; i < c; i++) {
        int s = csr_src[base + i];
        float w = csr_w[base + i];
        ushort4 v = *(const ushort4*)(t + (size_t)s * kFh + c0);
        a0 += w * jk_b2f(v.x);
        a1 += w * jk_b2f(v.y);
        a2 += w * jk_b2f(v.z);
        a3 += w * jk_b2f(v.w);
    }
    a0 += bias[c0 + 0]; a1 += bias[c0 + 1]; a2 += bias[c0 + 2]; a3 += bias[c0 + 3];
    ushort4 o;
    o.x = jk_f2b(a0); o.y = jk_f2b(a1); o.z = jk_f2b(a2); o.w = jk_f2b(a3);
    *(ushort4*)(h + (size_t)n * kFh + c0) = o;
}

__global__ void jk2_bnstats(const unsigned short* h, float* sum, float* sumsq) {
    int c = threadIdx.x;
    int r0 = blockIdx.x * 64;
    float s = 0.f, s2 = 0.f;
    int rend = r0 + 64 < kN ? r0 + 64 : kN;
    for (int r = r0; r < rend; r++) {
        float v = jk_b2f(h[(size_t)r * kFh + c]);
        s += v;
        s2 += v * v;
    }
    atomicAdd(&sum[c], s);
    atomicAdd(&sumsq[c], s2);
}

__global__ void jk2_bnfinal(const float* sum, const float* sumsq, const float* gamma,
                            const float* beta, int layer, float* scale, float* shift) {
    int c = threadIdx.x;
    float mean = sum[c] / (float)kN;
    float var = sumsq[c] / (float)kN - mean * mean;
    var = var < 0.f ? 0.f : var;
    float sc = gamma[layer * kFh + c] * rsqrtf(var + 1e-5f);
    scale[c] = sc;
    shift[c] = beta[layer * kFh + c] - mean * sc;
}

__global__ void jk2_bnapply(unsigned short* h, const float* scale, const float* shift) {
    int idx = blockIdx.x * blockDim.x + threadIdx.x;
    if (idx >= kN * 64) return;
    int c0 = (idx & 63) * 4;
    size_t o = (size_t)(idx >> 6) * kFh + c0;
    ushort4 u = *(ushort4*)(h + o);
    float v0 = jk_b2f(u.x) * scale[c0 + 0] + shift[c0 + 0];
    float v1 = jk_b2f(u.y) * scale[c0 + 1] + shift[c0 + 1];
    float v2 = jk_b2f(u.z) * scale[c0 + 2] + shift[c0 + 2];
    float v3 = jk_b2f(u.w) * scale[c0 + 3] + shift[c0 + 3];
    v0 = v0 > 0.f ? v0 : 0.f;
    v1 = v1 > 0.f ? v1 : 0.f;
    v2 = v2 > 0.f ? v2 : 0.f;
    v3 = v3 > 0.f ? v3 : 0.f;
    ushort4 w;
    w.x = jk_f2b(v0); w.y = jk_f2b(v1); w.z = jk_f2b(v2); w.w = jk_f2b(v3);
    *(ushort4*)(h + o) = w;
}

__global__ void jk2_zinit(float* z, const float* bout) {
    int idx = blockIdx.x * blockDim.x + threadIdx.x;
    if (idx < kN * kFout) z[idx] = bout[idx % kFout];
}

// z[kN x 40] += h[kN x 256] @ Wout[layer*256 .. +256, 40]
__global__ __launch_bounds__(256) void jk2_zacc(const unsigned short* h, const float* Wout,
                                                int layer, float* z) {
    __shared__ float Ws[256][40];
    __shared__ unsigned short Hs[32][264];  // pad 8 u16: breaks 32-way bank conflict on column reads
    int tid = threadIdx.x;
    for (int f = tid; f < kFh * kFout; f += 256) {
        int k = f / 40, c = f % 40;
        Ws[k][c] = Wout[(size_t)(layer * kFh + k) * kFout + c];
    }
    int row0 = blockIdx.x * 32;
    for (int f = tid; f < 1024; f += 256) {
        int r = f >> 5, k8 = (f & 31) * 8;
        int row = row0 + r;
        ushort4 a = make_ushort4(0, 0, 0, 0), b = make_ushort4(0, 0, 0, 0);
        if (row < kN) {
            a = *(const ushort4*)(h + (size_t)row * kFh + k8);
            b = *(const ushort4*)(h + (size_t)row * kFh + k8 + 4);
        }
        *(ushort4*)&Hs[r][k8] = a;
        *(ushort4*)&Hs[r][k8 + 4] = b;
    }
    __syncthreads();
    int q = tid & 7, rl = tid >> 3;
    int row = row0 + rl;
    if (row >= kN) return;
    float acc0 = 0.f, acc1 = 0.f, acc2 = 0.f, acc3 = 0.f, acc4 = 0.f;
    for (int k = 0; k < kFh; k++) {
        float a = jk_b2f(Hs[rl][k]);
        acc0 += a * Ws[k][q * 5 + 0];
        acc1 += a * Ws[k][q * 5 + 1];
        acc2 += a * Ws[k][q * 5 + 2];
        acc3 += a * Ws[k][q * 5 + 3];
        acc4 += a * Ws[k][q * 5 + 4];
    }
    float* zp = z + (size_t)row * kFout + q * 5;
    zp[0] += acc0; zp[1] += acc1; zp[2] += acc2; zp[3] += acc3; zp[4] += acc4;
}

// FINAL OUTPUT IS FLOAT32 (reference computes f32 log_softmax).
__global__ void jk2_lsm(const float* z, float* out) {
    int row = blockIdx.x * blockDim.x + threadIdx.x;
    if (row >= kN) return;
    float v[kFout];
    float m = -1e30f;
    for (int j = 0; j < kFout; j++) {
        v[j] = z[(size_t)row * kFout + j];
        m = fmaxf(m, v[j]);
    }
    float s = 0.f;
    for (int j = 0; j < kFout; j++) s += expf(v[j] - m);
    float ls = m + logf(s);
    for (int j = 0; j < kFout; j++) out[(size_t)row * kFout + j] = v[j] - ls;
}

extern "C" void kernel_launch(void* const* d_in, const int* in_sizes, int n_in,
                              void* d_out, int out_size, void* d_ws, size_t ws_size,
                              hipStream_t stream) {
    (void)in_sizes; (void)n_in; (void)out_size; (void)ws_size;
    const float* x = (const float*)d_in[0];
    const int* eb = (const int*)d_in[1];
    const float* W_in = (const float*)d_in[2];
    const float* b_in = (const float*)d_in[3];
    const float* W_hid = (const float*)d_in[4];
    const float* b_hid = (const float*)d_in[5];
    const float* gamma = (const float*)d_in[6];
    const float* beta = (const float*)d_in[7];
    const float* W_out = (const float*)d_in[8];
    const float* b_out = (const float*)d_in[9];
    float* out = (float*)d_out;

    char* p = (char*)d_ws;
    auto alloc = [&](size_t b) -> void* {
        void* r = (void*)p;
        p += (b + 255) & ~(size_t)255;
        return r;
    };
    int* flag = (int*)alloc(8);
    int* counts = (int*)alloc((size_t)kN * 4);
    int* off = (int*)alloc((size_t)kN * 4);
    int* pos = (int*)alloc((size_t)kN * 4);
    float* dinv = (float*)alloc((size_t)kN * 4);
    float* invdeg = (float*)alloc((size_t)kN * 4);
    float* bnsums = (float*)alloc(512 * 4);
    float* bnss = (float*)alloc(512 * 4);
    int* csr_src = (int*)alloc((size_t)kE * 4);
    float* csr_w = (float*)alloc((size_t)kE * 4);
    unsigned short* hA = (unsigned short*)alloc((size_t)kN * kFh * 2);
    unsigned short* hB = (unsigned short*)alloc((size_t)kN * kFh * 2);
    float* z = (float*)alloc((size_t)kN * kFout * 4);

    jk2_zero_i<<<(kN + 255) / 256, 256, 0, stream>>>(counts, kN);
    jk2_detect<<<1, 256, 0, stream>>>(eb, flag);
    jk2_count<<<2048, 256, 0, stream>>>(eb, flag, counts);
    jk2_nodeprep<<<(kN + 255) / 256, 256, 0, stream>>>(counts, dinv, invdeg, off, pos, flag + 1);
    jk2_fill<<<2048, 256, 0, stream>>>(eb, flag, dinv, pos, csr_src, csr_w);
    jk2_zinit<<<(kN * kFout + 255) / 256, 256, 0, stream>>>(z, b_out);

    for (int l = 0; l < kL; l++) {
        const float* W = (l == 0) ? W_in : W_hid + (size_t)(l - 1) * kFh * kFh;
        const float* b = (l == 0) ? b_in : b_hid + (size_t)(l - 1) * kFh;
        dim3 g((kN + 127) / 128, 4);
        if (l == 0)
            jk2_gemm_f32<<<g, 256, 0, stream>>>(x, W, hA);
        else
            jk2_gemm_bf<<<g, 256, 0, stream>>>(hB, W, hA);
        jk2_agg<<<(kN + 3) / 4, 256, 0, stream>>>(hA, b, off, counts, csr_src, csr_w, invdeg, hB);
        jk2_zero_f<<<2, 256, 0, stream>>>(bnsums, 512);
        jk2_bnstats<<<(kN + 63) / 64, 256, 0, stream>>>(hB, bnsums, bnsums + 256);
        jk2_bnfinal<<<1, 256, 0, stream>>>(bnsums, bnsums + 256, gamma, beta, l, bnss, bnss + 256);
        jk2_bnapply<<<(kN * 64 + 255) / 256, 256, 0, stream>>>(hB, bnss, bnss + 256);
        jk2_zacc<<<(kN + 31) / 32, 256, 0, stream>>>(hB, W_out, l, z);
    }
    jk2_lsm<<<(kN + 255) / 256, 256, 0, stream>>>(z, out);
}

// Round 4
// 2298.394 us; speedup vs baseline: 1.5170x; 1.5170x over previous
//
#include <hip/hip_runtime.h>
#include <math.h>

constexpr int kN = 170000;
constexpr int kE = 2720000;
constexpr int kFin = 128;
constexpr int kFh = 256;
constexpr int kL = 4;
constexpr int kFout = 40;

typedef __attribute__((ext_vector_type(8))) short bf16x8;
typedef __attribute__((ext_vector_type(4))) float f32x4;

__device__ __forceinline__ float jk_b2f(unsigned short u) {
    unsigned int x = ((unsigned int)u) << 16;
    float f;
    __builtin_memcpy(&f, &x, 4);
    return f;
}
__device__ __forceinline__ unsigned short jk_f2b(float f) {
    unsigned int x;
    __builtin_memcpy(&x, &f, 4);
    unsigned int r = (x + 0x7fffu + ((x >> 16) & 1u)) >> 16;
    return (unsigned short)r;
}

union U4 {
    uint4 v;
    unsigned short s[8];
};

__global__ void jk3_zero_i(int* p, int n) {
    int i = blockIdx.x * blockDim.x + threadIdx.x;
    if (i < n) p[i] = 0;
}
__global__ void jk3_zero_f(float* p, int n) {
    int i = blockIdx.x * blockDim.x + threadIdx.x;
    if (i < n) p[i] = 0.0f;
}

// flag[0] = 1 if edge buffer is int64 (read stride shift), else 0; flag[1]=0 cursor.
__global__ void jk3_detect(const int* eb, int* flag) {
    __shared__ int nz;
    if (threadIdx.x == 0) nz = 0;
    __syncthreads();
    int bad = 0;
    for (int j = 0; j < 4; j++) {
        int idx = threadIdx.x * 4 + j;
        if (eb[2 * idx + 1] != 0) bad = 1;
    }
    if (bad) atomicOr(&nz, 1);
    __syncthreads();
    if (threadIdx.x == 0) {
        flag[0] = nz ? 0 : 1;
        flag[1] = 0;
    }
}

__global__ void jk3_count(const int* eb, const int* flag, int* counts) {
    int s64 = flag[0];
    for (int e = blockIdx.x * blockDim.x + threadIdx.x; e < kE; e += gridDim.x * blockDim.x) {
        int d = eb[(kE + e) << s64];
        atomicAdd(&counts[d], 1);
    }
}

__global__ void jk3_nodeprep(const int* counts, float* dinv, float* invdeg, int* off, int* pos,
                             int* cursor) {
    int n = blockIdx.x * blockDim.x + threadIdx.x;
    if (n < kN) {
        int c = counts[n];
        float deg = (float)c + 1.0f;
        dinv[n] = rsqrtf(deg);
        invdeg[n] = 1.0f / deg;
        int o = atomicAdd(cursor, c);
        off[n] = o;
        pos[n] = o;
    }
}

__global__ void jk3_fill(const int* eb, const int* flag, const float* dinv, int* pos,
                         int* csr_src, float* csr_w) {
    int s64 = flag[0];
    for (int e = blockIdx.x * blockDim.x + threadIdx.x; e < kE; e += gridDim.x * blockDim.x) {
        int s = eb[e << s64];
        int d = eb[(kE + e) << s64];
        float w = dinv[s] * dinv[d];
        int p = atomicAdd(&pos[d], 1);
        csr_src[p] = s;
        csr_w[p] = w;
    }
}

// Wt[c][k] = bf16(W[k][c]);  W: [K][256] fp32, Wt: [256][K] bf16
__global__ void jk3_wt(const float* W, unsigned short* Wt, int K) {
    int idx = blockIdx.x * blockDim.x + threadIdx.x;
    if (idx >= K * kFh) return;
    int c = idx / K, k = idx % K;
    Wt[idx] = jk_f2b(W[(size_t)k * kFh + c]);
}

// C[bf16, kN x 256] = A[kN x K] @ W[K x 256], W given transposed bf16 Wt[256][K].
// AF32=1: A fp32, else A bf16. 128x128 tile, 4 waves of 64x64, mfma 16x16x32.
template <int AF32>
__global__ __launch_bounds__(256) void jk3_gemm(const void* Aptr, const unsigned short* Wt,
                                                unsigned short* C, int K) {
    __shared__ unsigned short As[128][40];  // pad 40 u16 = 80B rows: 16B-aligned, 20-bank stride
    __shared__ unsigned short Bs[128][40];
    int tid = threadIdx.x;
    int row0 = blockIdx.x * 128;
    int n0 = blockIdx.y * 128;
    int lane = tid & 63, w = tid >> 6;
    int wm = w >> 1, wn = w & 1;
    int lr = lane & 15, lg = lane >> 4;

    f32x4 acc[4][4];
#pragma unroll
    for (int i = 0; i < 4; i++)
#pragma unroll
        for (int j = 0; j < 4; j++) acc[i][j] = (f32x4){0.f, 0.f, 0.f, 0.f};

    int sr = tid >> 1;              // 0..127
    int skh = (tid & 1) * 16;       // 0 or 16

    for (int k0 = 0; k0 < K; k0 += 32) {
        // stage A: rows row0..+127, k k0..+31
        {
            int row = row0 + sr;
            if (AF32) {
                const float* A = (const float*)Aptr;
                unsigned short tmp[16];
                if (row < kN) {
                    const float* g = A + (size_t)row * K + k0 + skh;
#pragma unroll
                    for (int j = 0; j < 16; j++) tmp[j] = jk_f2b(g[j]);
                } else {
#pragma unroll
                    for (int j = 0; j < 16; j++) tmp[j] = 0;
                }
                *(uint4*)&As[sr][skh] = *(uint4*)&tmp[0];
                *(uint4*)&As[sr][skh + 8] = *(uint4*)&tmp[8];
            } else {
                const unsigned short* A = (const unsigned short*)Aptr;
                uint4 u0 = make_uint4(0, 0, 0, 0), u1 = make_uint4(0, 0, 0, 0);
                if (row < kN) {
                    const unsigned short* g = A + (size_t)row * K + k0 + skh;
                    u0 = *(const uint4*)g;
                    u1 = *(const uint4*)(g + 8);
                }
                *(uint4*)&As[sr][skh] = u0;
                *(uint4*)&As[sr][skh + 8] = u1;
            }
        }
        // stage B: Bs[c][k] from Wt[(n0+c)][k0..], coalesced 16B
        {
            const unsigned short* g = Wt + (size_t)(n0 + sr) * K + k0 + skh;
            *(uint4*)&Bs[sr][skh] = *(const uint4*)g;
            *(uint4*)&Bs[sr][skh + 8] = *(const uint4*)(g + 8);
        }
        __syncthreads();

        bf16x8 af[4], bfr[4];
#pragma unroll
        for (int mi = 0; mi < 4; mi++)
            af[mi] = *(const bf16x8*)&As[wm * 64 + mi * 16 + lr][lg * 8];
#pragma unroll
        for (int ni = 0; ni < 4; ni++)
            bfr[ni] = *(const bf16x8*)&Bs[wn * 64 + ni * 16 + lr][lg * 8];
#pragma unroll
        for (int mi = 0; mi < 4; mi++)
#pragma unroll
            for (int ni = 0; ni < 4; ni++)
                acc[mi][ni] = __builtin_amdgcn_mfma_f32_16x16x32_bf16(af[mi], bfr[ni],
                                                                      acc[mi][ni], 0, 0, 0);
        __syncthreads();
    }

#pragma unroll
    for (int mi = 0; mi < 4; mi++) {
#pragma unroll
        for (int j = 0; j < 4; j++) {
            int row = row0 + wm * 64 + mi * 16 + lg * 4 + j;
            if (row < kN) {
#pragma unroll
                for (int ni = 0; ni < 4; ni++) {
                    int col = n0 + wn * 64 + ni * 16 + lr;
                    C[(size_t)row * kFh + col] = jk_f2b(acc[mi][ni][j]);
                }
            }
        }
    }
}

// h[n,:] = sum_{e: dst=n} w_e * t[src_e,:] + t[n,:]*invdeg[n] + bias
// One wave per node. Lanes 0-31 / 32-63 each handle 8 channels x 2 edges per step
// (4 row-gathers in flight). Halves folded with shfl_xor(32).
__global__ __launch_bounds__(256) void jk3_agg(const unsigned short* t, const float* bias,
                                               const int* off, const int* cnt, const int* csr_src,
                                               const float* csr_w, const float* invdeg,
                                               unsigned short* h) {
    int n = blockIdx.x * 4 + (threadIdx.x >> 6);
    if (n >= kN) return;
    int l = threadIdx.x & 63;
    int half = l >> 5;
    int c0 = (l & 31) * 8;

    float acc[8];
    {
        // self term (half 0 weighted, half 1 zero — row n is cached anyway)
        U4 u;
        u.v = *(const uint4*)(t + (size_t)n * kFh + c0);
        float sw = half ? 0.0f : invdeg[n];
#pragma unroll
        for (int j = 0; j < 8; j++) acc[j] = sw * jk_b2f(u.s[j]);
    }

    int base = off[n], c = cnt[n];
    for (int i = 0; i < c; i += 4) {
        int ea = i + half * 2;
        int eb2 = ea + 1;
        bool va = ea < c, vb = eb2 < c;
        int ia = va ? base + ea : 0;
        int ib = vb ? base + eb2 : 0;
        int sa = csr_src[ia];
        int sb = csr_src[ib];
        float wa = va ? csr_w[ia] : 0.0f;
        float wb = vb ? csr_w[ib] : 0.0f;
        U4 ua, ub;
        ua.v = *(const uint4*)(t + (size_t)sa * kFh + c0);
        ub.v = *(const uint4*)(t + (size_t)sb * kFh + c0);
#pragma unroll
        for (int j = 0; j < 8; j++) acc[j] += wa * jk_b2f(ua.s[j]) + wb * jk_b2f(ub.s[j]);
    }

#pragma unroll
    for (int j = 0; j < 8; j++) acc[j] += __shfl_xor(acc[j], 32, 64);

    if (half == 0) {
        U4 o;
#pragma unroll
        for (int j = 0; j < 8; j++) o.s[j] = jk_f2b(acc[j] + bias[c0 + j]);
        *(uint4*)(h + (size_t)n * kFh + c0) = o.v;
    }
}

__global__ void jk3_bnstats(const unsigned short* h, float* sum, float* sumsq) {
    int c = threadIdx.x;
    int r0 = blockIdx.x * 64;
    float s = 0.f, s2 = 0.f;
    int rend = r0 + 64 < kN ? r0 + 64 : kN;
    for (int r = r0; r < rend; r++) {
        float v = jk_b2f(h[(size_t)r * kFh + c]);
        s += v;
        s2 += v * v;
    }
    atomicAdd(&sum[c], s);
    atomicAdd(&sumsq[c], s2);
}

__global__ void jk3_bnfinal(const float* sum, const float* sumsq, const float* gamma,
                            const float* beta, int layer, float* scale, float* shift) {
    int c = threadIdx.x;
    float mean = sum[c] / (float)kN;
    float var = sumsq[c] / (float)kN - mean * mean;
    var = var < 0.f ? 0.f : var;
    float sc = gamma[layer * kFh + c] * rsqrtf(var + 1e-5f);
    scale[c] = sc;
    shift[c] = beta[layer * kFh + c] - mean * sc;
}

// Fused: normalize+ReLU h in-place (bf16) AND z += h_norm @ Wout-slice.
// layer==0 initializes z = b_out + ...
__global__ __launch_bounds__(256) void jk3_zacc(unsigned short* h, const float* scale,
                                                const float* shift, const float* Wout, int layer,
                                                const float* bout, float* z) {
    __shared__ float Ws[256][40];
    __shared__ unsigned short Hs[32][264];
    int tid = threadIdx.x;
    for (int f = tid; f < kFh * kFout; f += 256) {
        int k = f / 40, c = f % 40;
        Ws[k][c] = Wout[(size_t)(layer * kFh + k) * kFout + c];
    }
    int row0 = blockIdx.x * 32;
    // stage + normalize + write-back
    for (int f = tid; f < 1024; f += 256) {
        int r = f >> 5, k8 = (f & 31) * 8;
        int row = row0 + r;
        U4 u, o;
        if (row < kN) {
            u.v = *(const uint4*)(h + (size_t)row * kFh + k8);
#pragma unroll
            for (int j = 0; j < 8; j++) {
                float v = jk_b2f(u.s[j]) * scale[k8 + j] + shift[k8 + j];
                v = v > 0.f ? v : 0.f;
                o.s[j] = jk_f2b(v);
            }
            *(uint4*)(h + (size_t)row * kFh + k8) = o.v;
        } else {
#pragma unroll
            for (int j = 0; j < 8; j++) o.s[j] = 0;
        }
        *(uint4*)&Hs[r][k8] = o.v;
    }
    __syncthreads();
    int q = tid & 7, rl = tid >> 3;
    int row = row0 + rl;
    if (row >= kN) return;
    float a0 = 0.f, a1 = 0.f, a2 = 0.f, a3 = 0.f, a4 = 0.f;
    for (int k = 0; k < kFh; k++) {
        float a = jk_b2f(Hs[rl][k]);
        a0 += a * Ws[k][q * 5 + 0];
        a1 += a * Ws[k][q * 5 + 1];
        a2 += a * Ws[k][q * 5 + 2];
        a3 += a * Ws[k][q * 5 + 3];
        a4 += a * Ws[k][q * 5 + 4];
    }
    float* zp = z + (size_t)row * kFout + q * 5;
    if (layer == 0) {
        const float* bp = bout + q * 5;
        zp[0] = a0 + bp[0]; zp[1] = a1 + bp[1]; zp[2] = a2 + bp[2];
        zp[3] = a3 + bp[3]; zp[4] = a4 + bp[4];
    } else {
        zp[0] += a0; zp[1] += a1; zp[2] += a2; zp[3] += a3; zp[4] += a4;
    }
}

// log_softmax, 8 threads per row (5 cols each), group reduce via shfl_xor.
__global__ void jk3_lsm(const float* z, float* out) {
    int gid = blockIdx.x * blockDim.x + threadIdx.x;
    int row = gid >> 3, sub = gid & 7;
    if (row >= kN) return;
    const float* zp = z + (size_t)row * kFout + sub * 5;
    float v0 = zp[0], v1 = zp[1], v2 = zp[2], v3 = zp[3], v4 = zp[4];
    float m = fmaxf(fmaxf(fmaxf(v0, v1), fmaxf(v2, v3)), v4);
    m = fmaxf(m, __shfl_xor(m, 1, 64));
    m = fmaxf(m, __shfl_xor(m, 2, 64));
    m = fmaxf(m, __shfl_xor(m, 4, 64));
    float s = expf(v0 - m) + expf(v1 - m) + expf(v2 - m) + expf(v3 - m) + expf(v4 - m);
    s += __shfl_xor(s, 1, 64);
    s += __shfl_xor(s, 2, 64);
    s += __shfl_xor(s, 4, 64);
    float ls = m + logf(s);
    float* op = out + (size_t)row * kFout + sub * 5;
    op[0] = v0 - ls; op[1] = v1 - ls; op[2] = v2 - ls; op[3] = v3 - ls; op[4] = v4 - ls;
}

extern "C" void kernel_launch(void* const* d_in, const int* in_sizes, int n_in,
                              void* d_out, int out_size, void* d_ws, size_t ws_size,
                              hipStream_t stream) {
    (void)in_sizes; (void)n_in; (void)out_size; (void)ws_size;
    const float* x = (const float*)d_in[0];
    const int* eb = (const int*)d_in[1];
    const float* W_in = (const float*)d_in[2];
    const float* b_in = (const float*)d_in[3];
    const float* W_hid = (const float*)d_in[4];
    const float* b_hid = (const float*)d_in[5];
    const float* gamma = (const float*)d_in[6];
    const float* beta = (const float*)d_in[7];
    const float* W_out = (const float*)d_in[8];
    const float* b_out = (const float*)d_in[9];
    float* out = (float*)d_out;

    char* p = (char*)d_ws;
    auto alloc = [&](size_t b) -> void* {
        void* r = (void*)p;
        p += (b + 255) & ~(size_t)255;
        return r;
    };
    int* flag = (int*)alloc(8);
    int* counts = (int*)alloc((size_t)kN * 4);
    int* off = (int*)alloc((size_t)kN * 4);
    int* pos = (int*)alloc((size_t)kN * 4);
    float* dinv = (float*)alloc((size_t)kN * 4);
    float* invdeg = (float*)alloc((size_t)kN * 4);
    float* bnsums = (float*)alloc(512 * 4);
    float* bnss = (float*)alloc(512 * 4);
    int* csr_src = (int*)alloc((size_t)kE * 4);
    float* csr_w = (float*)alloc((size_t)kE * 4);
    unsigned short* hA = (unsigned short*)alloc((size_t)kN * kFh * 2);
    unsigned short* hB = (unsigned short*)alloc((size_t)kN * kFh * 2);
    float* z = (float*)alloc((size_t)kN * kFout * 4);
    unsigned short* Wt0 = (unsigned short*)alloc((size_t)kFin * kFh * 2);
    unsigned short* Wt1 = (unsigned short*)alloc((size_t)kFh * kFh * 2);
    unsigned short* Wt2 = (unsigned short*)alloc((size_t)kFh * kFh * 2);
    unsigned short* Wt3 = (unsigned short*)alloc((size_t)kFh * kFh * 2);

    jk3_zero_i<<<(kN + 255) / 256, 256, 0, stream>>>(counts, kN);
    jk3_detect<<<1, 256, 0, stream>>>(eb, flag);
    jk3_count<<<2048, 256, 0, stream>>>(eb, flag, counts);
    jk3_nodeprep<<<(kN + 255) / 256, 256, 0, stream>>>(counts, dinv, invdeg, off, pos, flag + 1);
    jk3_fill<<<2048, 256, 0, stream>>>(eb, flag, dinv, pos, csr_src, csr_w);

    jk3_wt<<<(kFin * kFh + 255) / 256, 256, 0, stream>>>(W_in, Wt0, kFin);
    jk3_wt<<<(kFh * kFh + 255) / 256, 256, 0, stream>>>(W_hid, Wt1, kFh);
    jk3_wt<<<(kFh * kFh + 255) / 256, 256, 0, stream>>>(W_hid + (size_t)kFh * kFh, Wt2, kFh);
    jk3_wt<<<(kFh * kFh + 255) / 256, 256, 0, stream>>>(W_hid + (size_t)2 * kFh * kFh, Wt3, kFh);

    unsigned short* Wts[4] = {Wt0, Wt1, Wt2, Wt3};
    dim3 gg((kN + 127) / 128, 2);
    for (int l = 0; l < kL; l++) {
        const float* b = (l == 0) ? b_in : b_hid + (size_t)(l - 1) * kFh;
        int K = (l == 0) ? kFin : kFh;
        if (l == 0)
            jk3_gemm<1><<<gg, 256, 0, stream>>>(x, Wts[l], hA, K);
        else
            jk3_gemm<0><<<gg, 256, 0, stream>>>(hB, Wts[l], hA, K);
        jk3_agg<<<(kN + 3) / 4, 256, 0, stream>>>(hA, b, off, counts, csr_src, csr_w, invdeg, hB);
        jk3_zero_f<<<2, 256, 0, stream>>>(bnsums, 512);
        jk3_bnstats<<<(kN + 63) / 64, 256, 0, stream>>>(hB, bnsums, bnsums + 256);
        jk3_bnfinal<<<1, 256, 0, stream>>>(bnsums, bnsums + 256, gamma, beta, l, bnss, bnss + 256);
        jk3_zacc<<<(kN + 31) / 32, 256, 0, stream>>>(hB, bnss, bnss + 256, W_out, l, b_out, z);
    }
    jk3_lsm<<<(kN * 8 + 255) / 256, 256, 0, stream>>>(z, out);
}

// Round 5
// 2131.621 us; speedup vs baseline: 1.6357x; 1.0782x over previous
//
#include <hip/hip_runtime.h>
#include <math.h>

constexpr int kN = 170000;
constexpr int kE = 2720000;
constexpr int kFin = 128;
constexpr int kFh = 256;
constexpr int kL = 4;
constexpr int kFout = 40;

typedef __attribute__((ext_vector_type(8))) short bf16x8;
typedef __attribute__((ext_vector_type(4))) float f32x4;

__device__ __forceinline__ float jk_b2f(unsigned short u) {
    unsigned int x = ((unsigned int)u) << 16;
    float f;
    __builtin_memcpy(&f, &x, 4);
    return f;
}
__device__ __forceinline__ unsigned short jk_f2b(float f) {
    unsigned int x;
    __builtin_memcpy(&x, &f, 4);
    unsigned int r = (x + 0x7fffu + ((x >> 16) & 1u)) >> 16;
    return (unsigned short)r;
}

union U4 {
    uint4 v;
    unsigned short s[8];
};

__global__ void jk4_zero_i(int* p, int n) {
    int i = blockIdx.x * blockDim.x + threadIdx.x;
    if (i < n) p[i] = 0;
}
__global__ void jk4_zero_f(float* p, int n) {
    int i = blockIdx.x * blockDim.x + threadIdx.x;
    if (i < n) p[i] = 0.0f;
}

// flag[0] = 1 if edge buffer is int64 (element stride shift), else 0; flag[1]=0 cursor.
__global__ void jk4_detect(const int* eb, int* flag) {
    __shared__ int nz;
    if (threadIdx.x == 0) nz = 0;
    __syncthreads();
    int bad = 0;
    for (int j = 0; j < 4; j++) {
        int idx = threadIdx.x * 4 + j;
        if (eb[2 * idx + 1] != 0) bad = 1;
    }
    if (bad) atomicOr(&nz, 1);
    __syncthreads();
    if (threadIdx.x == 0) {
        flag[0] = nz ? 0 : 1;
        flag[1] = 0;
    }
}

__global__ void jk4_count(const int* eb, const int* flag, int* counts) {
    int e = blockIdx.x * blockDim.x + threadIdx.x;
    if (e >= kE) return;
    int s64 = flag[0];
    int d = eb[(kE + e) << s64];
    atomicAdd(&counts[d], 1);
}

__global__ void jk4_nodeprep(const int* counts, float* dinv, float* invdeg, int* off, int* pos,
                             int* cursor) {
    int n = blockIdx.x * blockDim.x + threadIdx.x;
    if (n < kN) {
        int c = counts[n];
        float deg = (float)c + 1.0f;
        dinv[n] = rsqrtf(deg);
        invdeg[n] = 1.0f / deg;
        int o = atomicAdd(cursor, c);
        off[n] = o;
        pos[n] = o;
    }
}

// Bucket-fill src indices only (w recomputed in agg from dinv).
__global__ void jk4_fill(const int* eb, const int* flag, int* pos, int* csr_src) {
    int e = blockIdx.x * blockDim.x + threadIdx.x;
    if (e >= kE) return;
    int s64 = flag[0];
    int s = eb[e << s64];
    int d = eb[(kE + e) << s64];
    int p = atomicAdd(&pos[d], 1);
    csr_src[p] = s;
}

// Wt[c][k] = bf16(W[k][c]);  W: [K][256] fp32, Wt: [256][K] bf16
__global__ void jk4_wt(const float* W, unsigned short* Wt, int K) {
    int idx = blockIdx.x * blockDim.x + threadIdx.x;
    if (idx >= K * kFh) return;
    int c = idx / K, k = idx % K;
    Wt[idx] = jk_f2b(W[(size_t)k * kFh + c]);
}

// Wout slice [l] -> transposed hi/lo bf16 pair: Wto[(l*2+hl)*48 + col][k], cols 40..47 zero.
__global__ void jk4_wtout(const float* Wout, unsigned short* Wto) {
    int idx = blockIdx.x * blockDim.x + threadIdx.x;
    if (idx >= kL * 48 * 256) return;
    int l = idx / (48 * 256);
    int rem = idx % (48 * 256);
    int col = rem >> 8, k = rem & 255;
    float wv = (col < kFout) ? Wout[(size_t)(l * kFh + k) * kFout + col] : 0.f;
    unsigned short hi = jk_f2b(wv);
    float res = wv - jk_b2f(hi);
    unsigned short lo = jk_f2b(res);
    Wto[((size_t)(l * 2 + 0) * 48 + col) * 256 + k] = hi;
    Wto[((size_t)(l * 2 + 1) * 48 + col) * 256 + k] = lo;
}

// C[bf16, kN x 256] = A[kN x K] @ W, W given transposed bf16 Wt[256][K].
// 128x128 tile, 4 waves of 64x64, mfma 16x16x32. (unchanged from jk3 — verified)
template <int AF32>
__global__ __launch_bounds__(256) void jk4_gemm(const void* Aptr, const unsigned short* Wt,
                                                unsigned short* C, int K) {
    __shared__ unsigned short As[128][40];
    __shared__ unsigned short Bs[128][40];
    int tid = threadIdx.x;
    int row0 = blockIdx.x * 128;
    int n0 = blockIdx.y * 128;
    int lane = tid & 63, w = tid >> 6;
    int wm = w >> 1, wn = w & 1;
    int lr = lane & 15, lg = lane >> 4;

    f32x4 acc[4][4];
#pragma unroll
    for (int i = 0; i < 4; i++)
#pragma unroll
        for (int j = 0; j < 4; j++) acc[i][j] = (f32x4){0.f, 0.f, 0.f, 0.f};

    int sr = tid >> 1;
    int skh = (tid & 1) * 16;

    for (int k0 = 0; k0 < K; k0 += 32) {
        {
            int row = row0 + sr;
            if (AF32) {
                const float* A = (const float*)Aptr;
                unsigned short tmp[16];
                if (row < kN) {
                    const float* g = A + (size_t)row * K + k0 + skh;
#pragma unroll
                    for (int j = 0; j < 16; j++) tmp[j] = jk_f2b(g[j]);
                } else {
#pragma unroll
                    for (int j = 0; j < 16; j++) tmp[j] = 0;
                }
                *(uint4*)&As[sr][skh] = *(uint4*)&tmp[0];
                *(uint4*)&As[sr][skh + 8] = *(uint4*)&tmp[8];
            } else {
                const unsigned short* A = (const unsigned short*)Aptr;
                uint4 u0 = make_uint4(0, 0, 0, 0), u1 = make_uint4(0, 0, 0, 0);
                if (row < kN) {
                    const unsigned short* g = A + (size_t)row * K + k0 + skh;
                    u0 = *(const uint4*)g;
                    u1 = *(const uint4*)(g + 8);
                }
                *(uint4*)&As[sr][skh] = u0;
                *(uint4*)&As[sr][skh + 8] = u1;
            }
        }
        {
            const unsigned short* g = Wt + (size_t)(n0 + sr) * K + k0 + skh;
            *(uint4*)&Bs[sr][skh] = *(const uint4*)g;
            *(uint4*)&Bs[sr][skh + 8] = *(const uint4*)(g + 8);
        }
        __syncthreads();

        bf16x8 af[4], bfr[4];
#pragma unroll
        for (int mi = 0; mi < 4; mi++)
            af[mi] = *(const bf16x8*)&As[wm * 64 + mi * 16 + lr][lg * 8];
#pragma unroll
        for (int ni = 0; ni < 4; ni++)
            bfr[ni] = *(const bf16x8*)&Bs[wn * 64 + ni * 16 + lr][lg * 8];
#pragma unroll
        for (int mi = 0; mi < 4; mi++)
#pragma unroll
            for (int ni = 0; ni < 4; ni++)
                acc[mi][ni] = __builtin_amdgcn_mfma_f32_16x16x32_bf16(af[mi], bfr[ni],
                                                                      acc[mi][ni], 0, 0, 0);
        __syncthreads();
    }

#pragma unroll
    for (int mi = 0; mi < 4; mi++) {
#pragma unroll
        for (int j = 0; j < 4; j++) {
            int row = row0 + wm * 64 + mi * 16 + lg * 4 + j;
            if (row < kN) {
#pragma unroll
                for (int ni = 0; ni < 4; ni++) {
                    int col = n0 + wn * 64 + ni * 16 + lr;
                    C[(size_t)row * kFh + col] = jk_f2b(acc[mi][ni][j]);
                }
            }
        }
    }
}

// h[n,:] = sum_{e: dst=n} dinv[s]*dinv[n] * t[s,:] + t[n,:]*invdeg[n] + bias
// One wave/node; each half-wave keeps 4 row-gathers in flight (8/wave).
__global__ __launch_bounds__(256) void jk4_agg(const unsigned short* t, const float* bias,
                                               const int* off, const int* cnt, const int* csr_src,
                                               const float* dinv, const float* invdeg,
                                               unsigned short* h) {
    int n = blockIdx.x * 4 + (threadIdx.x >> 6);
    if (n >= kN) return;
    int l = threadIdx.x & 63;
    int half = l >> 5;
    int c0 = (l & 31) * 8;

    float acc[8];
    {
        U4 u;
        u.v = *(const uint4*)(t + (size_t)n * kFh + c0);
        float sw = half ? 0.0f : invdeg[n];
#pragma unroll
        for (int j = 0; j < 8; j++) acc[j] = sw * jk_b2f(u.s[j]);
    }

    int base = off[n], c = cnt[n];
    float dn = dinv[n];
    for (int i = 0; i < c; i += 8) {
        int e0 = i + half * 4;
        float w[4];
        U4 uu[4];
#pragma unroll
        for (int q = 0; q < 4; q++) {
            int e = e0 + q;
            bool v = e < c;
            int src = n;
            if (v) src = csr_src[base + e];       // invalid lanes fall back to hot self-row
            w[q] = v ? dinv[src] * dn : 0.0f;
            uu[q].v = *(const uint4*)(t + (size_t)src * kFh + c0);
        }
#pragma unroll
        for (int q = 0; q < 4; q++)
#pragma unroll
            for (int j = 0; j < 8; j++) acc[j] += w[q] * jk_b2f(uu[q].s[j]);
    }

#pragma unroll
    for (int j = 0; j < 8; j++) acc[j] += __shfl_xor(acc[j], 32, 64);

    if (half == 0) {
        U4 o;
#pragma unroll
        for (int j = 0; j < 8; j++) o.s[j] = jk_f2b(acc[j] + bias[c0 + j]);
        *(uint4*)(h + (size_t)n * kFh + c0) = o.v;
    }
}

__global__ void jk4_bnstats(const unsigned short* h, float* sum, float* sumsq) {
    int c = threadIdx.x;
    int r0 = blockIdx.x * 64;
    float s = 0.f, s2 = 0.f;
    int rend = r0 + 64 < kN ? r0 + 64 : kN;
    for (int r = r0; r < rend; r++) {
        float v = jk_b2f(h[(size_t)r * kFh + c]);
        s += v;
        s2 += v * v;
    }
    atomicAdd(&sum[c], s);
    atomicAdd(&sumsq[c], s2);
}

__global__ void jk4_bnfinal(const float* sum, const float* sumsq, const float* gamma,
                            const float* beta, int layer, float* scale, float* shift) {
    int c = threadIdx.x;
    float mean = sum[c] / (float)kN;
    float var = sumsq[c] / (float)kN - mean * mean;
    var = var < 0.f ? 0.f : var;
    float sc = gamma[layer * kFh + c] * rsqrtf(var + 1e-5f);
    scale[c] = sc;
    shift[c] = beta[layer * kFh + c] - mean * sc;
}

// MFMA zacc: normalize+ReLU h (write back unless LAST), z += h_norm @ WoutSlice
// (Wout as hi/lo bf16 for f32-grade accuracy). LAST fuses log-softmax -> out.
// Block: 256 thr / 4 waves, 128 rows; per wave 32 rows (2 m-tiles) x 48 cols (3 n-tiles).
template <int FIRST, int LAST>
__global__ __launch_bounds__(256) void jk4_zacc(unsigned short* h, const float* scale,
                                                const float* shift, const unsigned short* Wto,
                                                const float* bout, float* z, float* out) {
    __shared__ unsigned short Bs[2][48][264];
    __shared__ unsigned short As[128][40];
    __shared__ float ssc[256], ssh[256];
    int tid = threadIdx.x;
    for (int f = tid; f < 2 * 48 * 256; f += 256) {
        int hl = f / (48 * 256);
        int rem = f % (48 * 256);
        Bs[hl][rem >> 8][rem & 255] = Wto[f];
    }
    ssc[tid] = scale[tid];
    ssh[tid] = shift[tid];
    __syncthreads();

    int row0 = blockIdx.x * 128;
    int w = tid >> 6, lane = tid & 63;
    int lr = lane & 15, lg = lane >> 4;
    int sr = tid >> 1, skh = (tid & 1) * 16;

    f32x4 acc[2][3];
#pragma unroll
    for (int mi = 0; mi < 2; mi++)
#pragma unroll
        for (int ni = 0; ni < 3; ni++) acc[mi][ni] = (f32x4){0.f, 0.f, 0.f, 0.f};

    for (int k0 = 0; k0 < kFh; k0 += 32) {
        int row = row0 + sr;
        U4 o0, o1;
        if (row < kN) {
            U4 u0, u1;
            const unsigned short* g = h + (size_t)row * kFh + k0 + skh;
            u0.v = *(const uint4*)g;
            u1.v = *(const uint4*)(g + 8);
#pragma unroll
            for (int j = 0; j < 8; j++) {
                float v = jk_b2f(u0.s[j]) * ssc[k0 + skh + j] + ssh[k0 + skh + j];
                o0.s[j] = jk_f2b(v > 0.f ? v : 0.f);
            }
#pragma unroll
            for (int j = 0; j < 8; j++) {
                float v = jk_b2f(u1.s[j]) * ssc[k0 + skh + 8 + j] + ssh[k0 + skh + 8 + j];
                o1.s[j] = jk_f2b(v > 0.f ? v : 0.f);
            }
            if (!LAST) {
                *(uint4*)(h + (size_t)row * kFh + k0 + skh) = o0.v;
                *(uint4*)(h + (size_t)row * kFh + k0 + skh + 8) = o1.v;
            }
        } else {
#pragma unroll
            for (int j = 0; j < 8; j++) { o0.s[j] = 0; o1.s[j] = 0; }
        }
        *(uint4*)&As[sr][skh] = o0.v;
        *(uint4*)&As[sr][skh + 8] = o1.v;
        __syncthreads();

        bf16x8 af[2], bh[3], bl[3];
#pragma unroll
        for (int mi = 0; mi < 2; mi++)
            af[mi] = *(const bf16x8*)&As[w * 32 + mi * 16 + lr][lg * 8];
#pragma unroll
        for (int ni = 0; ni < 3; ni++) {
            bh[ni] = *(const bf16x8*)&Bs[0][ni * 16 + lr][k0 + lg * 8];
            bl[ni] = *(const bf16x8*)&Bs[1][ni * 16 + lr][k0 + lg * 8];
        }
#pragma unroll
        for (int mi = 0; mi < 2; mi++)
#pragma unroll
            for (int ni = 0; ni < 3; ni++) {
                acc[mi][ni] = __builtin_amdgcn_mfma_f32_16x16x32_bf16(af[mi], bh[ni],
                                                                      acc[mi][ni], 0, 0, 0);
                acc[mi][ni] = __builtin_amdgcn_mfma_f32_16x16x32_bf16(af[mi], bl[ni],
                                                                      acc[mi][ni], 0, 0, 0);
            }
        __syncthreads();
    }

#pragma unroll
    for (int mi = 0; mi < 2; mi++) {
#pragma unroll
        for (int j = 0; j < 4; j++) {
            int row = row0 + w * 32 + mi * 16 + lg * 4 + j;
            if (row >= kN) continue;
            if (!LAST) {
#pragma unroll
                for (int ni = 0; ni < 3; ni++) {
                    int col = ni * 16 + lr;
                    if (col < kFout) {
                        if (FIRST)
                            z[(size_t)row * kFout + col] = acc[mi][ni][j] + bout[col];
                        else
                            z[(size_t)row * kFout + col] += acc[mi][ni][j];
                    }
                }
            } else {
                const float* zp = z + (size_t)row * kFout;
                float v0 = zp[lr] + acc[mi][0][j];
                float v1 = zp[16 + lr] + acc[mi][1][j];
                float v2 = (lr < 8) ? (zp[32 + lr] + acc[mi][2][j]) : -1e30f;
                float m = fmaxf(fmaxf(v0, v1), v2);
                m = fmaxf(m, __shfl_xor(m, 1, 64));
                m = fmaxf(m, __shfl_xor(m, 2, 64));
                m = fmaxf(m, __shfl_xor(m, 4, 64));
                m = fmaxf(m, __shfl_xor(m, 8, 64));
                float s = expf(v0 - m) + expf(v1 - m) + ((lr < 8) ? expf(v2 - m) : 0.f);
                s += __shfl_xor(s, 1, 64);
                s += __shfl_xor(s, 2, 64);
                s += __shfl_xor(s, 4, 64);
                s += __shfl_xor(s, 8, 64);
                float ls = m + logf(s);
                float* op = out + (size_t)row * kFout;
                op[lr] = v0 - ls;
                op[16 + lr] = v1 - ls;
                if (lr < 8) op[32 + lr] = v2 - ls;
            }
        }
    }
}

extern "C" void kernel_launch(void* const* d_in, const int* in_sizes, int n_in,
                              void* d_out, int out_size, void* d_ws, size_t ws_size,
                              hipStream_t stream) {
    (void)in_sizes; (void)n_in; (void)out_size; (void)ws_size;
    const float* x = (const float*)d_in[0];
    const int* eb = (const int*)d_in[1];
    const float* W_in = (const float*)d_in[2];
    const float* b_in = (const float*)d_in[3];
    const float* W_hid = (const float*)d_in[4];
    const float* b_hid = (const float*)d_in[5];
    const float* gamma = (const float*)d_in[6];
    const float* beta = (const float*)d_in[7];
    const float* W_out = (const float*)d_in[8];
    const float* b_out = (const float*)d_in[9];
    float* out = (float*)d_out;

    char* p = (char*)d_ws;
    auto alloc = [&](size_t b) -> void* {
        void* r = (void*)p;
        p += (b + 255) & ~(size_t)255;
        return r;
    };
    int* flag = (int*)alloc(8);
    int* counts = (int*)alloc((size_t)kN * 4);
    int* off = (int*)alloc((size_t)kN * 4);
    int* pos = (int*)alloc((size_t)kN * 4);
    float* dinv = (float*)alloc((size_t)kN * 4);
    float* invdeg = (float*)alloc((size_t)kN * 4);
    float* bnsums = (float*)alloc(512 * 4);
    float* bnss = (float*)alloc(512 * 4);
    int* csr_src = (int*)alloc((size_t)kE * 4);
    unsigned short* hA = (unsigned short*)alloc((size_t)kN * kFh * 2);
    unsigned short* hB = (unsigned short*)alloc((size_t)kN * kFh * 2);
    float* z = (float*)alloc((size_t)kN * kFout * 4);
    unsigned short* Wt0 = (unsigned short*)alloc((size_t)kFin * kFh * 2);
    unsigned short* Wt1 = (unsigned short*)alloc((size_t)kFh * kFh * 2);
    unsigned short* Wt2 = (unsigned short*)alloc((size_t)kFh * kFh * 2);
    unsigned short* Wt3 = (unsigned short*)alloc((size_t)kFh * kFh * 2);
    unsigned short* Wto = (unsigned short*)alloc((size_t)kL * 2 * 48 * 256 * 2);

    jk4_zero_i<<<(kN + 255) / 256, 256, 0, stream>>>(counts, kN);
    jk4_detect<<<1, 256, 0, stream>>>(eb, flag);
    jk4_count<<<(kE + 255) / 256, 256, 0, stream>>>(eb, flag, counts);
    jk4_nodeprep<<<(kN + 255) / 256, 256, 0, stream>>>(counts, dinv, invdeg, off, pos, flag + 1);
    jk4_fill<<<(kE + 255) / 256, 256, 0, stream>>>(eb, flag, pos, csr_src);

    jk4_wt<<<(kFin * kFh + 255) / 256, 256, 0, stream>>>(W_in, Wt0, kFin);
    jk4_wt<<<(kFh * kFh + 255) / 256, 256, 0, stream>>>(W_hid, Wt1, kFh);
    jk4_wt<<<(kFh * kFh + 255) / 256, 256, 0, stream>>>(W_hid + (size_t)kFh * kFh, Wt2, kFh);
    jk4_wt<<<(kFh * kFh + 255) / 256, 256, 0, stream>>>(W_hid + (size_t)2 * kFh * kFh, Wt3, kFh);
    jk4_wtout<<<(kL * 48 * 256 + 255) / 256, 256, 0, stream>>>(W_out, Wto);

    unsigned short* Wts[4] = {Wt0, Wt1, Wt2, Wt3};
    dim3 gg((kN + 127) / 128, 2);
    int zg = (kN + 127) / 128;
    for (int l = 0; l < kL; l++) {
        const float* b = (l == 0) ? b_in : b_hid + (size_t)(l - 1) * kFh;
        int K = (l == 0) ? kFin : kFh;
        if (l == 0)
            jk4_gemm<1><<<gg, 256, 0, stream>>>(x, Wts[l], hA, K);
        else
            jk4_gemm<0><<<gg, 256, 0, stream>>>(hB, Wts[l], hA, K);
        jk4_agg<<<(kN + 3) / 4, 256, 0, stream>>>(hA, b, off, counts, csr_src, dinv, invdeg, hB);
        jk4_zero_f<<<2, 256, 0, stream>>>(bnsums, 512);
        jk4_bnstats<<<(kN + 63) / 64, 256, 0, stream>>>(hB, bnsums, bnsums + 256);
        jk4_bnfinal<<<1, 256, 0, stream>>>(bnsums, bnsums + 256, gamma, beta, l, bnss, bnss + 256);
        const unsigned short* wtl = Wto + (size_t)l * 2 * 48 * 256;
        if (l == 0)
            jk4_zacc<1, 0><<<zg, 256, 0, stream>>>(hB, bnss, bnss + 256, wtl, b_out, z, out);
        else if (l < kL - 1)
            jk4_zacc<0, 0><<<zg, 256, 0, stream>>>(hB, bnss, bnss + 256, wtl, b_out, z, out);
        else
            jk4_zacc<0, 1><<<zg, 256, 0, stream>>>(hB, bnss, bnss + 256, wtl, b_out, z, out);
    }
}

// Round 6
// 1924.274 us; speedup vs baseline: 1.8119x; 1.1078x over previous
//
#include <hip/hip_runtime.h>
#include <math.h>

constexpr int kN = 170000;
constexpr int kE = 2720000;
constexpr int kFin = 128;
constexpr int kFh = 256;
constexpr int kL = 4;
constexpr int kFout = 40;

typedef __attribute__((ext_vector_type(8))) short bf16x8;
typedef __attribute__((ext_vector_type(4))) float f32x4;

__device__ __forceinline__ float jk_b2f(unsigned short u) {
    unsigned int x = ((unsigned int)u) << 16;
    float f;
    __builtin_memcpy(&f, &x, 4);
    return f;
}
__device__ __forceinline__ unsigned short jk_f2b(float f) {
    unsigned int x;
    __builtin_memcpy(&x, &f, 4);
    unsigned int r = (x + 0x7fffu + ((x >> 16) & 1u)) >> 16;
    return (unsigned short)r;
}

union U4 {
    uint4 v;
    unsigned short s[8];
};

__global__ void jk5_zero_i(int* p, int n) {
    int i = blockIdx.x * blockDim.x + threadIdx.x;
    if (i < n) p[i] = 0;
}
__global__ void jk5_zero_f(float* p, int n) {
    int i = blockIdx.x * blockDim.x + threadIdx.x;
    if (i < n) p[i] = 0.0f;
}

// flag[0] = 1 if edge buffer is int64 (element stride shift), else 0; flag[1]=0 cursor.
__global__ void jk5_detect(const int* eb, int* flag) {
    __shared__ int nz;
    if (threadIdx.x == 0) nz = 0;
    __syncthreads();
    int bad = 0;
    for (int j = 0; j < 4; j++) {
        int idx = threadIdx.x * 4 + j;
        if (eb[2 * idx + 1] != 0) bad = 1;
    }
    if (bad) atomicOr(&nz, 1);
    __syncthreads();
    if (threadIdx.x == 0) {
        flag[0] = nz ? 0 : 1;
        flag[1] = 0;
    }
}

// counts[d]++ and remember each edge's rank within its dst bucket.
__global__ void jk5_count(const int* eb, const int* flag, int* counts, int* rank) {
    int e = blockIdx.x * blockDim.x + threadIdx.x;
    if (e >= kE) return;
    int s64 = flag[0];
    int d = eb[(kE + e) << s64];
    rank[e] = atomicAdd(&counts[d], 1);
}

__global__ void jk5_nodeprep(const int* counts, float* dinv, float* invdeg, int* off,
                             int* cursor) {
    int n = blockIdx.x * blockDim.x + threadIdx.x;
    if (n < kN) {
        int c = counts[n];
        float deg = (float)c + 1.0f;
        dinv[n] = rsqrtf(deg);
        invdeg[n] = 1.0f / deg;
        off[n] = atomicAdd(cursor, c);
    }
}

// Atomic-free bucket fill: p = off[d] + rank[e].
__global__ void jk5_fill(const int* eb, const int* flag, const int* rank, const int* off,
                         const float* dinv, int* csr_src, float* csr_w) {
    int e = blockIdx.x * blockDim.x + threadIdx.x;
    if (e >= kE) return;
    int s64 = flag[0];
    int s = eb[e << s64];
    int d = eb[(kE + e) << s64];
    int p = off[d] + rank[e];
    csr_src[p] = s;
    csr_w[p] = dinv[s] * dinv[d];
}

// Wt[c][k] = bf16(W[k][c]);  W: [K][256] fp32, Wt: [256][K] bf16
__global__ void jk5_wt(const float* W, unsigned short* Wt, int K) {
    int idx = blockIdx.x * blockDim.x + threadIdx.x;
    if (idx >= K * kFh) return;
    int c = idx / K, k = idx % K;
    Wt[idx] = jk_f2b(W[(size_t)k * kFh + c]);
}

// Wout slice [l] -> transposed hi/lo bf16 pair: Wto[(l*2+hl)*48 + col][k], cols 40..47 zero.
__global__ void jk5_wtout(const float* Wout, unsigned short* Wto) {
    int idx = blockIdx.x * blockDim.x + threadIdx.x;
    if (idx >= kL * 48 * 256) return;
    int l = idx / (48 * 256);
    int rem = idx % (48 * 256);
    int col = rem >> 8, k = rem & 255;
    float wv = (col < kFout) ? Wout[(size_t)(l * kFh + k) * kFout + col] : 0.f;
    unsigned short hi = jk_f2b(wv);
    float res = wv - jk_b2f(hi);
    unsigned short lo = jk_f2b(res);
    Wto[((size_t)(l * 2 + 0) * 48 + col) * 256 + k] = hi;
    Wto[((size_t)(l * 2 + 1) * 48 + col) * 256 + k] = lo;
}

// C[bf16, kN x 256] = A[kN x K] @ W, W transposed bf16 Wt[256][K]. (verified r4/r5)
template <int AF32>
__global__ __launch_bounds__(256) void jk5_gemm(const void* Aptr, const unsigned short* Wt,
                                                unsigned short* C, int K) {
    __shared__ unsigned short As[128][40];
    __shared__ unsigned short Bs[128][40];
    int tid = threadIdx.x;
    int row0 = blockIdx.x * 128;
    int n0 = blockIdx.y * 128;
    int lane = tid & 63, w = tid >> 6;
    int wm = w >> 1, wn = w & 1;
    int lr = lane & 15, lg = lane >> 4;

    f32x4 acc[4][4];
#pragma unroll
    for (int i = 0; i < 4; i++)
#pragma unroll
        for (int j = 0; j < 4; j++) acc[i][j] = (f32x4){0.f, 0.f, 0.f, 0.f};

    int sr = tid >> 1;
    int skh = (tid & 1) * 16;

    for (int k0 = 0; k0 < K; k0 += 32) {
        {
            int row = row0 + sr;
            if (AF32) {
                const float* A = (const float*)Aptr;
                unsigned short tmp[16];
                if (row < kN) {
                    const float* g = A + (size_t)row * K + k0 + skh;
#pragma unroll
                    for (int j = 0; j < 16; j++) tmp[j] = jk_f2b(g[j]);
                } else {
#pragma unroll
                    for (int j = 0; j < 16; j++) tmp[j] = 0;
                }
                *(uint4*)&As[sr][skh] = *(uint4*)&tmp[0];
                *(uint4*)&As[sr][skh + 8] = *(uint4*)&tmp[8];
            } else {
                const unsigned short* A = (const unsigned short*)Aptr;
                uint4 u0 = make_uint4(0, 0, 0, 0), u1 = make_uint4(0, 0, 0, 0);
                if (row < kN) {
                    const unsigned short* g = A + (size_t)row * K + k0 + skh;
                    u0 = *(const uint4*)g;
                    u1 = *(const uint4*)(g + 8);
                }
                *(uint4*)&As[sr][skh] = u0;
                *(uint4*)&As[sr][skh + 8] = u1;
            }
        }
        {
            const unsigned short* g = Wt + (size_t)(n0 + sr) * K + k0 + skh;
            *(uint4*)&Bs[sr][skh] = *(const uint4*)g;
            *(uint4*)&Bs[sr][skh + 8] = *(const uint4*)(g + 8);
        }
        __syncthreads();

        bf16x8 af[4], bfr[4];
#pragma unroll
        for (int mi = 0; mi < 4; mi++)
            af[mi] = *(const bf16x8*)&As[wm * 64 + mi * 16 + lr][lg * 8];
#pragma unroll
        for (int ni = 0; ni < 4; ni++)
            bfr[ni] = *(const bf16x8*)&Bs[wn * 64 + ni * 16 + lr][lg * 8];
#pragma unroll
        for (int mi = 0; mi < 4; mi++)
#pragma unroll
            for (int ni = 0; ni < 4; ni++)
                acc[mi][ni] = __builtin_amdgcn_mfma_f32_16x16x32_bf16(af[mi], bfr[ni],
                                                                      acc[mi][ni], 0, 0, 0);
        __syncthreads();
    }

#pragma unroll
    for (int mi = 0; mi < 4; mi++) {
#pragma unroll
        for (int j = 0; j < 4; j++) {
            int row = row0 + wm * 64 + mi * 16 + lg * 4 + j;
            if (row < kN) {
#pragma unroll
                for (int ni = 0; ni < 4; ni++) {
                    int col = n0 + wn * 64 + ni * 16 + lr;
                    C[(size_t)row * kFh + col] = jk_f2b(acc[mi][ni][j]);
                }
            }
        }
    }
}

// h[n,:] = sum_e w_e * t[src_e,:] + t[n,:]*invdeg[n] + bias; fused BN-stat partials.
// 32 lanes per node (lane handles 8 channels), 4 edges in flight per group.
// Grid-stride; per-thread register stats -> LDS -> global atomics once per block.
__global__ __launch_bounds__(256) void jk5_agg(const unsigned short* t, const float* bias,
                                               const int* off, const int* cnt, const int* csr_src,
                                               const float* csr_w, const float* invdeg,
                                               unsigned short* h, float* stats) {
    __shared__ float lsum[256], lsq[256];
    int tid = threadIdx.x;
    lsum[tid] = 0.f;
    lsq[tid] = 0.f;
    int lane32 = tid & 31;
    int grp = tid >> 5;
    int c0 = lane32 * 8;
    float bs[8];
#pragma unroll
    for (int j = 0; j < 8; j++) bs[j] = bias[c0 + j];

    float rsum[8] = {}, rsq[8] = {};

    for (int n = blockIdx.x * 8 + grp; n < kN; n += gridDim.x * 8) {
        float acc[8];
        {
            U4 u;
            u.v = *(const uint4*)(t + (size_t)n * kFh + c0);
            float sw = invdeg[n];
#pragma unroll
            for (int j = 0; j < 8; j++) acc[j] = sw * jk_b2f(u.s[j]);
        }
        int base = off[n], c = cnt[n];
        for (int i = 0; i < c; i += 4) {
            float w[4];
            U4 uu[4];
#pragma unroll
            for (int q = 0; q < 4; q++) {
                int e = i + q;
                bool v = e < c;
                int idx = v ? base + e : base;
                int src = csr_src[idx];
                w[q] = v ? csr_w[idx] : 0.0f;
                uu[q].v = *(const uint4*)(t + (size_t)src * kFh + c0);
            }
#pragma unroll
            for (int q = 0; q < 4; q++)
#pragma unroll
                for (int j = 0; j < 8; j++) acc[j] += w[q] * jk_b2f(uu[q].s[j]);
        }
        U4 o;
#pragma unroll
        for (int j = 0; j < 8; j++) {
            float v = acc[j] + bs[j];
            rsum[j] += v;
            rsq[j] += v * v;
            o.s[j] = jk_f2b(v);
        }
        *(uint4*)(h + (size_t)n * kFh + c0) = o.v;
    }

    __syncthreads();  // zeroing (top) and all loop work complete
#pragma unroll
    for (int j = 0; j < 8; j++) {
        atomicAdd(&lsum[c0 + j], rsum[j]);
        atomicAdd(&lsq[c0 + j], rsq[j]);
    }
    __syncthreads();
    atomicAdd(&stats[tid], lsum[tid]);
    atomicAdd(&stats[256 + tid], lsq[tid]);
}

__global__ void jk5_bnfinal(const float* stats, const float* gamma, const float* beta, int layer,
                            float* scale, float* shift) {
    int c = threadIdx.x;
    float mean = stats[c] / (float)kN;
    float var = stats[256 + c] / (float)kN - mean * mean;
    var = var < 0.f ? 0.f : var;
    float sc = gamma[layer * kFh + c] * rsqrtf(var + 1e-5f);
    scale[c] = sc;
    shift[c] = beta[layer * kFh + c] - mean * sc;
}

// MFMA zacc: normalize+ReLU h (write back unless LAST), z += h_norm @ WoutSlice.
// LAST fuses log-softmax -> out. (verified r5)
template <int FIRST, int LAST>
__global__ __launch_bounds__(256) void jk5_zacc(unsigned short* h, const float* scale,
                                                const float* shift, const unsigned short* Wto,
                                                const float* bout, float* z, float* out) {
    __shared__ unsigned short Bs[2][48][264];
    __shared__ unsigned short As[128][40];
    __shared__ float ssc[256], ssh[256];
    int tid = threadIdx.x;
    for (int f = tid; f < 2 * 48 * 256; f += 256) {
        int hl = f / (48 * 256);
        int rem = f % (48 * 256);
        Bs[hl][rem >> 8][rem & 255] = Wto[f];
    }
    ssc[tid] = scale[tid];
    ssh[tid] = shift[tid];
    __syncthreads();

    int row0 = blockIdx.x * 128;
    int w = tid >> 6, lane = tid & 63;
    int lr = lane & 15, lg = lane >> 4;
    int sr = tid >> 1, skh = (tid & 1) * 16;

    f32x4 acc[2][3];
#pragma unroll
    for (int mi = 0; mi < 2; mi++)
#pragma unroll
        for (int ni = 0; ni < 3; ni++) acc[mi][ni] = (f32x4){0.f, 0.f, 0.f, 0.f};

    for (int k0 = 0; k0 < kFh; k0 += 32) {
        int row = row0 + sr;
        U4 o0, o1;
        if (row < kN) {
            U4 u0, u1;
            const unsigned short* g = h + (size_t)row * kFh + k0 + skh;
            u0.v = *(const uint4*)g;
            u1.v = *(const uint4*)(g + 8);
#pragma unroll
            for (int j = 0; j < 8; j++) {
                float v = jk_b2f(u0.s[j]) * ssc[k0 + skh + j] + ssh[k0 + skh + j];
                o0.s[j] = jk_f2b(v > 0.f ? v : 0.f);
            }
#pragma unroll
            for (int j = 0; j < 8; j++) {
                float v = jk_b2f(u1.s[j]) * ssc[k0 + skh + 8 + j] + ssh[k0 + skh + 8 + j];
                o1.s[j] = jk_f2b(v > 0.f ? v : 0.f);
            }
            if (!LAST) {
                *(uint4*)(h + (size_t)row * kFh + k0 + skh) = o0.v;
                *(uint4*)(h + (size_t)row * kFh + k0 + skh + 8) = o1.v;
            }
        } else {
#pragma unroll
            for (int j = 0; j < 8; j++) { o0.s[j] = 0; o1.s[j] = 0; }
        }
        *(uint4*)&As[sr][skh] = o0.v;
        *(uint4*)&As[sr][skh + 8] = o1.v;
        __syncthreads();

        bf16x8 af[2], bh[3], bl[3];
#pragma unroll
        for (int mi = 0; mi < 2; mi++)
            af[mi] = *(const bf16x8*)&As[w * 32 + mi * 16 + lr][lg * 8];
#pragma unroll
        for (int ni = 0; ni < 3; ni++) {
            bh[ni] = *(const bf16x8*)&Bs[0][ni * 16 + lr][k0 + lg * 8];
            bl[ni] = *(const bf16x8*)&Bs[1][ni * 16 + lr][k0 + lg * 8];
        }
#pragma unroll
        for (int mi = 0; mi < 2; mi++)
#pragma unroll
            for (int ni = 0; ni < 3; ni++) {
                acc[mi][ni] = __builtin_amdgcn_mfma_f32_16x16x32_bf16(af[mi], bh[ni],
                                                                      acc[mi][ni], 0, 0, 0);
                acc[mi][ni] = __builtin_amdgcn_mfma_f32_16x16x32_bf16(af[mi], bl[ni],
                                                                      acc[mi][ni], 0, 0, 0);
            }
        __syncthreads();
    }

#pragma unroll
    for (int mi = 0; mi < 2; mi++) {
#pragma unroll
        for (int j = 0; j < 4; j++) {
            int row = row0 + w * 32 + mi * 16 + lg * 4 + j;
            if (row >= kN) continue;
            if (!LAST) {
#pragma unroll
                for (int ni = 0; ni < 3; ni++) {
                    int col = ni * 16 + lr;
                    if (col < kFout) {
                        if (FIRST)
                            z[(size_t)row * kFout + col] = acc[mi][ni][j] + bout[col];
                        else
                            z[(size_t)row * kFout + col] += acc[mi][ni][j];
                    }
                }
            } else {
                const float* zp = z + (size_t)row * kFout;
                float v0 = zp[lr] + acc[mi][0][j];
                float v1 = zp[16 + lr] + acc[mi][1][j];
                float v2 = (lr < 8) ? (zp[32 + lr] + acc[mi][2][j]) : -1e30f;
                float m = fmaxf(fmaxf(v0, v1), v2);
                m = fmaxf(m, __shfl_xor(m, 1, 64));
                m = fmaxf(m, __shfl_xor(m, 2, 64));
                m = fmaxf(m, __shfl_xor(m, 4, 64));
                m = fmaxf(m, __shfl_xor(m, 8, 64));
                float s = expf(v0 - m) + expf(v1 - m) + ((lr < 8) ? expf(v2 - m) : 0.f);
                s += __shfl_xor(s, 1, 64);
                s += __shfl_xor(s, 2, 64);
                s += __shfl_xor(s, 4, 64);
                s += __shfl_xor(s, 8, 64);
                float ls = m + logf(s);
                float* op = out + (size_t)row * kFout;
                op[lr] = v0 - ls;
                op[16 + lr] = v1 - ls;
                if (lr < 8) op[32 + lr] = v2 - ls;
            }
        }
    }
}

extern "C" void kernel_launch(void* const* d_in, const int* in_sizes, int n_in,
                              void* d_out, int out_size, void* d_ws, size_t ws_size,
                              hipStream_t stream) {
    (void)in_sizes; (void)n_in; (void)out_size; (void)ws_size;
    const float* x = (const float*)d_in[0];
    const int* eb = (const int*)d_in[1];
    const float* W_in = (const float*)d_in[2];
    const float* b_in = (const float*)d_in[3];
    const float* W_hid = (const float*)d_in[4];
    const float* b_hid = (const float*)d_in[5];
    const float* gamma = (const float*)d_in[6];
    const float* beta = (const float*)d_in[7];
    const float* W_out = (const float*)d_in[8];
    const float* b_out = (const float*)d_in[9];
    float* out = (float*)d_out;

    char* p = (char*)d_ws;
    auto alloc = [&](size_t b) -> void* {
        void* r = (void*)p;
        p += (b + 255) & ~(size_t)255;
        return r;
    };
    int* flag = (int*)alloc(8);
    int* counts = (int*)alloc((size_t)kN * 4);
    int* off = (int*)alloc((size_t)kN * 4);
    float* dinv = (float*)alloc((size_t)kN * 4);
    float* invdeg = (float*)alloc((size_t)kN * 4);
    float* bnsums = (float*)alloc((size_t)kL * 512 * 4);   // per-layer sum/sumsq
    float* bnss = (float*)alloc((size_t)kL * 512 * 4);     // per-layer scale/shift
    int* rank = (int*)alloc((size_t)kE * 4);
    int* csr_src = (int*)alloc((size_t)kE * 4);
    float* csr_w = (float*)alloc((size_t)kE * 4);
    unsigned short* hA = (unsigned short*)alloc((size_t)kN * kFh * 2);
    unsigned short* hB = (unsigned short*)alloc((size_t)kN * kFh * 2);
    float* z = (float*)alloc((size_t)kN * kFout * 4);
    unsigned short* Wt0 = (unsigned short*)alloc((size_t)kFin * kFh * 2);
    unsigned short* Wt1 = (unsigned short*)alloc((size_t)kFh * kFh * 2);
    unsigned short* Wt2 = (unsigned short*)alloc((size_t)kFh * kFh * 2);
    unsigned short* Wt3 = (unsigned short*)alloc((size_t)kFh * kFh * 2);
    unsigned short* Wto = (unsigned short*)alloc((size_t)kL * 2 * 48 * 256 * 2);

    jk5_zero_i<<<(kN + 255) / 256, 256, 0, stream>>>(counts, kN);
    jk5_zero_f<<<(kL * 512 + 255) / 256, 256, 0, stream>>>(bnsums, kL * 512);
    jk5_detect<<<1, 256, 0, stream>>>(eb, flag);
    jk5_count<<<(kE + 255) / 256, 256, 0, stream>>>(eb, flag, counts, rank);
    jk5_nodeprep<<<(kN + 255) / 256, 256, 0, stream>>>(counts, dinv, invdeg, off, flag + 1);
    jk5_fill<<<(kE + 255) / 256, 256, 0, stream>>>(eb, flag, rank, off, dinv, csr_src, csr_w);

    jk5_wt<<<(kFin * kFh + 255) / 256, 256, 0, stream>>>(W_in, Wt0, kFin);
    jk5_wt<<<(kFh * kFh + 255) / 256, 256, 0, stream>>>(W_hid, Wt1, kFh);
    jk5_wt<<<(kFh * kFh + 255) / 256, 256, 0, stream>>>(W_hid + (size_t)kFh * kFh, Wt2, kFh);
    jk5_wt<<<(kFh * kFh + 255) / 256, 256, 0, stream>>>(W_hid + (size_t)2 * kFh * kFh, Wt3, kFh);
    jk5_wtout<<<(kL * 48 * 256 + 255) / 256, 256, 0, stream>>>(W_out, Wto);

    unsigned short* Wts[4] = {Wt0, Wt1, Wt2, Wt3};
    dim3 gg((kN + 127) / 128, 2);
    int zg = (kN + 127) / 128;
    for (int l = 0; l < kL; l++) {
        const float* b = (l == 0) ? b_in : b_hid + (size_t)(l - 1) * kFh;
        int K = (l == 0) ? kFin : kFh;
        if (l == 0)
            jk5_gemm<1><<<gg, 256, 0, stream>>>(x, Wts[l], hA, K);
        else
            jk5_gemm<0><<<gg, 256, 0, stream>>>(hB, Wts[l], hA, K);
        jk5_agg<<<2560, 256, 0, stream>>>(hA, b, off, counts, csr_src, csr_w, invdeg, hB,
                                          bnsums + (size_t)l * 512);
        jk5_bnfinal<<<1, 256, 0, stream>>>(bnsums + (size_t)l * 512, gamma, beta, l,
                                           bnss + (size_t)l * 512, bnss + (size_t)l * 512 + 256);
        const unsigned short* wtl = Wto + (size_t)l * 2 * 48 * 256;
        float* sc = bnss + (size_t)l * 512;
        if (l == 0)
            jk5_zacc<1, 0><<<zg, 256, 0, stream>>>(hB, sc, sc + 256, wtl, b_out, z, out);
        else if (l < kL - 1)
            jk5_zacc<0, 0><<<zg, 256, 0, stream>>>(hB, sc, sc + 256, wtl, b_out, z, out);
        else
            jk5_zacc<0, 1><<<zg, 256, 0, stream>>>(hB, sc, sc + 256, wtl, b_out, z, out);
    }
}

// Round 7
// 1802.267 us; speedup vs baseline: 1.9346x; 1.0677x over previous
//
#include <hip/hip_runtime.h>
#include <math.h>

constexpr int kN = 170000;
constexpr int kE = 2720000;
constexpr int kFin = 128;
constexpr int kFh = 256;
constexpr int kL = 4;
constexpr int kFout = 40;

typedef __attribute__((ext_vector_type(8))) short bf16x8;
typedef __attribute__((ext_vector_type(4))) float f32x4;

__device__ __forceinline__ float jk_b2f(unsigned short u) {
    unsigned int x = ((unsigned int)u) << 16;
    float f;
    __builtin_memcpy(&f, &x, 4);
    return f;
}
__device__ __forceinline__ unsigned short jk_f2b(float f) {
    unsigned int x;
    __builtin_memcpy(&x, &f, 4);
    unsigned int r = (x + 0x7fffu + ((x >> 16) & 1u)) >> 16;
    return (unsigned short)r;
}

union U4 {
    uint4 v;
    unsigned short s[8];
};

__global__ void jk6_zero_i(int* p, int n) {
    int i = blockIdx.x * blockDim.x + threadIdx.x;
    if (i < n) p[i] = 0;
}
__global__ void jk6_zero_f(float* p, int n) {
    int i = blockIdx.x * blockDim.x + threadIdx.x;
    if (i < n) p[i] = 0.0f;
}

// flag[0] = 1 if edge buffer is int64 (element stride shift), else 0; flag[1]=0 cursor.
__global__ void jk6_detect(const int* eb, int* flag) {
    __shared__ int nz;
    if (threadIdx.x == 0) nz = 0;
    __syncthreads();
    int bad = 0;
    for (int j = 0; j < 4; j++) {
        int idx = threadIdx.x * 4 + j;
        if (eb[2 * idx + 1] != 0) bad = 1;
    }
    if (bad) atomicOr(&nz, 1);
    __syncthreads();
    if (threadIdx.x == 0) {
        flag[0] = nz ? 0 : 1;
        flag[1] = 0;
    }
}

// counts[d]++ and remember each edge's rank within its dst bucket.
__global__ void jk6_count(const int* eb, const int* flag, int* counts, int* rank) {
    int e = blockIdx.x * blockDim.x + threadIdx.x;
    if (e >= kE) return;
    int s64 = flag[0];
    int d = eb[(kE + e) << s64];
    rank[e] = atomicAdd(&counts[d], 1);
}

__global__ void jk6_nodeprep(const int* counts, float* dinv, float* invdeg, int* off,
                             int* cursor) {
    int n = blockIdx.x * blockDim.x + threadIdx.x;
    if (n < kN) {
        int c = counts[n];
        float deg = (float)c + 1.0f;
        dinv[n] = rsqrtf(deg);
        invdeg[n] = 1.0f / deg;
        off[n] = atomicAdd(cursor, c);
    }
}

// Atomic-free bucket fill: p = off[d] + rank[e].
__global__ void jk6_fill(const int* eb, const int* flag, const int* rank, const int* off,
                         const float* dinv, int* csr_src, float* csr_w) {
    int e = blockIdx.x * blockDim.x + threadIdx.x;
    if (e >= kE) return;
    int s64 = flag[0];
    int s = eb[e << s64];
    int d = eb[(kE + e) << s64];
    int p = off[d] + rank[e];
    csr_src[p] = s;
    csr_w[p] = dinv[s] * dinv[d];
}

// Wt[c][k] = bf16(W[k][c]);  W: [K][256] fp32, Wt: [256][K] bf16
__global__ void jk6_wt(const float* W, unsigned short* Wt, int K) {
    int idx = blockIdx.x * blockDim.x + threadIdx.x;
    if (idx >= K * kFh) return;
    int c = idx / K, k = idx % K;
    Wt[idx] = jk_f2b(W[(size_t)k * kFh + c]);
}

// Wout slice [l] -> transposed hi/lo bf16 pair.
__global__ void jk6_wtout(const float* Wout, unsigned short* Wto) {
    int idx = blockIdx.x * blockDim.x + threadIdx.x;
    if (idx >= kL * 48 * 256) return;
    int l = idx / (48 * 256);
    int rem = idx % (48 * 256);
    int col = rem >> 8, k = rem & 255;
    float wv = (col < kFout) ? Wout[(size_t)(l * kFh + k) * kFout + col] : 0.f;
    unsigned short hi = jk_f2b(wv);
    float res = wv - jk_b2f(hi);
    unsigned short lo = jk_f2b(res);
    Wto[((size_t)(l * 2 + 0) * 48 + col) * 256 + k] = hi;
    Wto[((size_t)(l * 2 + 1) * 48 + col) * 256 + k] = lo;
}

// C[bf16, kN x 256] = A[kN x K] @ W, W transposed bf16 Wt[256][K]. (verified r4-r6)
template <int AF32>
__global__ __launch_bounds__(256) void jk6_gemm(const void* Aptr, const unsigned short* Wt,
                                                unsigned short* C, int K) {
    __shared__ unsigned short As[128][40];
    __shared__ unsigned short Bs[128][40];
    int tid = threadIdx.x;
    int row0 = blockIdx.x * 128;
    int n0 = blockIdx.y * 128;
    int lane = tid & 63, w = tid >> 6;
    int wm = w >> 1, wn = w & 1;
    int lr = lane & 15, lg = lane >> 4;

    f32x4 acc[4][4];
#pragma unroll
    for (int i = 0; i < 4; i++)
#pragma unroll
        for (int j = 0; j < 4; j++) acc[i][j] = (f32x4){0.f, 0.f, 0.f, 0.f};

    int sr = tid >> 1;
    int skh = (tid & 1) * 16;

    for (int k0 = 0; k0 < K; k0 += 32) {
        {
            int row = row0 + sr;
            if (AF32) {
                const float* A = (const float*)Aptr;
                unsigned short tmp[16];
                if (row < kN) {
                    const float* g = A + (size_t)row * K + k0 + skh;
#pragma unroll
                    for (int j = 0; j < 16; j++) tmp[j] = jk_f2b(g[j]);
                } else {
#pragma unroll
                    for (int j = 0; j < 16; j++) tmp[j] = 0;
                }
                *(uint4*)&As[sr][skh] = *(uint4*)&tmp[0];
                *(uint4*)&As[sr][skh + 8] = *(uint4*)&tmp[8];
            } else {
                const unsigned short* A = (const unsigned short*)Aptr;
                uint4 u0 = make_uint4(0, 0, 0, 0), u1 = make_uint4(0, 0, 0, 0);
                if (row < kN) {
                    const unsigned short* g = A + (size_t)row * K + k0 + skh;
                    u0 = *(const uint4*)g;
                    u1 = *(const uint4*)(g + 8);
                }
                *(uint4*)&As[sr][skh] = u0;
                *(uint4*)&As[sr][skh + 8] = u1;
            }
        }
        {
            const unsigned short* g = Wt + (size_t)(n0 + sr) * K + k0 + skh;
            *(uint4*)&Bs[sr][skh] = *(const uint4*)g;
            *(uint4*)&Bs[sr][skh + 8] = *(const uint4*)(g + 8);
        }
        __syncthreads();

        bf16x8 af[4], bfr[4];
#pragma unroll
        for (int mi = 0; mi < 4; mi++)
            af[mi] = *(const bf16x8*)&As[wm * 64 + mi * 16 + lr][lg * 8];
#pragma unroll
        for (int ni = 0; ni < 4; ni++)
            bfr[ni] = *(const bf16x8*)&Bs[wn * 64 + ni * 16 + lr][lg * 8];
#pragma unroll
        for (int mi = 0; mi < 4; mi++)
#pragma unroll
            for (int ni = 0; ni < 4; ni++)
                acc[mi][ni] = __builtin_amdgcn_mfma_f32_16x16x32_bf16(af[mi], bfr[ni],
                                                                      acc[mi][ni], 0, 0, 0);
        __syncthreads();
    }

#pragma unroll
    for (int mi = 0; mi < 4; mi++) {
#pragma unroll
        for (int j = 0; j < 4; j++) {
            int row = row0 + wm * 64 + mi * 16 + lg * 4 + j;
            if (row < kN) {
#pragma unroll
                for (int ni = 0; ni < 4; ni++) {
                    int col = n0 + wn * 64 + ni * 16 + lr;
                    C[(size_t)row * kFh + col] = jk_f2b(acc[mi][ni][j]);
                }
            }
        }
    }
}

// h[n,:] = sum_e w_e * t[src_e,:] + t[n,:]*invdeg[n] + bias.
// One wave per node (42500 blocks); each half-wave keeps 4 edges in flight
// (8 gathers/wave). csr_w precomputed (sequential). Fold halves via shfl_xor(32).
__global__ __launch_bounds__(256) void jk6_agg(const unsigned short* t, const float* bias,
                                               const int* off, const int* cnt, const int* csr_src,
                                               const float* csr_w, const float* invdeg,
                                               unsigned short* h) {
    int n = blockIdx.x * 4 + (threadIdx.x >> 6);
    if (n >= kN) return;
    int l = threadIdx.x & 63;
    int half = l >> 5;
    int c0 = (l & 31) * 8;

    float acc[8];
    {
        U4 u;
        u.v = *(const uint4*)(t + (size_t)n * kFh + c0);
        float sw = half ? 0.0f : invdeg[n];
#pragma unroll
        for (int j = 0; j < 8; j++) acc[j] = sw * jk_b2f(u.s[j]);
    }

    int base = off[n], c = cnt[n];
    for (int i = 0; i < c; i += 8) {
        int e0 = i + half * 4;
        float w[4];
        U4 uu[4];
#pragma unroll
        for (int q = 0; q < 4; q++) {
            int e = e0 + q;
            bool v = e < c;
            int idx = v ? base + e : base;
            int src = csr_src[idx];
            w[q] = v ? csr_w[idx] : 0.0f;
            uu[q].v = *(const uint4*)(t + (size_t)src * kFh + c0);
        }
#pragma unroll
        for (int q = 0; q < 4; q++)
#pragma unroll
            for (int j = 0; j < 8; j++) acc[j] += w[q] * jk_b2f(uu[q].s[j]);
    }

#pragma unroll
    for (int j = 0; j < 8; j++) acc[j] += __shfl_xor(acc[j], 32, 64);

    if (half == 0) {
        U4 o;
#pragma unroll
        for (int j = 0; j < 8; j++) o.s[j] = jk_f2b(acc[j] + bias[c0 + j]);
        *(uint4*)(h + (size_t)n * kFh + c0) = o.v;
    }
}

// Column sums/sumsq of h (bf16 [kN][256]) -> stats[0..255]=sum, [256..511]=sumsq.
// Grid-stride, uint4 loads, register accum -> LDS -> one global atomic set per block.
__global__ __launch_bounds__(256) void jk6_bnstats(const unsigned short* h, float* stats) {
    __shared__ float lsum[256], lsq[256];
    int tid = threadIdx.x;
    lsum[tid] = 0.f;
    lsq[tid] = 0.f;
    __syncthreads();
    int c0 = (tid & 31) * 8;
    int grp = tid >> 5;
    float rs[8] = {}, rq[8] = {};
    for (int n = blockIdx.x * 8 + grp; n < kN; n += gridDim.x * 8) {
        U4 u;
        u.v = *(const uint4*)(h + (size_t)n * kFh + c0);
#pragma unroll
        for (int j = 0; j < 8; j++) {
            float v = jk_b2f(u.s[j]);
            rs[j] += v;
            rq[j] += v * v;
        }
    }
#pragma unroll
    for (int j = 0; j < 8; j++) {
        atomicAdd(&lsum[c0 + j], rs[j]);
        atomicAdd(&lsq[c0 + j], rq[j]);
    }
    __syncthreads();
    atomicAdd(&stats[tid], lsum[tid]);
    atomicAdd(&stats[256 + tid], lsq[tid]);
}

__global__ void jk6_bnfinal(const float* stats, const float* gamma, const float* beta, int layer,
                            float* scale, float* shift) {
    int c = threadIdx.x;
    float mean = stats[c] / (float)kN;
    float var = stats[256 + c] / (float)kN - mean * mean;
    var = var < 0.f ? 0.f : var;
    float sc = gamma[layer * kFh + c] * rsqrtf(var + 1e-5f);
    scale[c] = sc;
    shift[c] = beta[layer * kFh + c] - mean * sc;
}

// MFMA zacc: normalize+ReLU h (write back unless LAST), z += h_norm @ WoutSlice.
// LAST fuses log-softmax -> out. (verified r5/r6)
template <int FIRST, int LAST>
__global__ __launch_bounds__(256) void jk6_zacc(unsigned short* h, const float* scale,
                                                const float* shift, const unsigned short* Wto,
                                                const float* bout, float* z, float* out) {
    __shared__ unsigned short Bs[2][48][264];
    __shared__ unsigned short As[128][40];
    __shared__ float ssc[256], ssh[256];
    int tid = threadIdx.x;
    for (int f = tid; f < 2 * 48 * 256; f += 256) {
        int hl = f / (48 * 256);
        int rem = f % (48 * 256);
        Bs[hl][rem >> 8][rem & 255] = Wto[f];
    }
    ssc[tid] = scale[tid];
    ssh[tid] = shift[tid];
    __syncthreads();

    int row0 = blockIdx.x * 128;
    int w = tid >> 6, lane = tid & 63;
    int lr = lane & 15, lg = lane >> 4;
    int sr = tid >> 1, skh = (tid & 1) * 16;

    f32x4 acc[2][3];
#pragma unroll
    for (int mi = 0; mi < 2; mi++)
#pragma unroll
        for (int ni = 0; ni < 3; ni++) acc[mi][ni] = (f32x4){0.f, 0.f, 0.f, 0.f};

    for (int k0 = 0; k0 < kFh; k0 += 32) {
        int row = row0 + sr;
        U4 o0, o1;
        if (row < kN) {
            U4 u0, u1;
            const unsigned short* g = h + (size_t)row * kFh + k0 + skh;
            u0.v = *(const uint4*)g;
            u1.v = *(const uint4*)(g + 8);
#pragma unroll
            for (int j = 0; j < 8; j++) {
                float v = jk_b2f(u0.s[j]) * ssc[k0 + skh + j] + ssh[k0 + skh + j];
                o0.s[j] = jk_f2b(v > 0.f ? v : 0.f);
            }
#pragma unroll
            for (int j = 0; j < 8; j++) {
                float v = jk_b2f(u1.s[j]) * ssc[k0 + skh + 8 + j] + ssh[k0 + skh + 8 + j];
                o1.s[j] = jk_f2b(v > 0.f ? v : 0.f);
            }
            if (!LAST) {
                *(uint4*)(h + (size_t)row * kFh + k0 + skh) = o0.v;
                *(uint4*)(h + (size_t)row * kFh + k0 + skh + 8) = o1.v;
            }
        } else {
#pragma unroll
            for (int j = 0; j < 8; j++) { o0.s[j] = 0; o1.s[j] = 0; }
        }
        *(uint4*)&As[sr][skh] = o0.v;
        *(uint4*)&As[sr][skh + 8] = o1.v;
        __syncthreads();

        bf16x8 af[2], bh[3], bl[3];
#pragma unroll
        for (int mi = 0; mi < 2; mi++)
            af[mi] = *(const bf16x8*)&As[w * 32 + mi * 16 + lr][lg * 8];
#pragma unroll
        for (int ni = 0; ni < 3; ni++) {
            bh[ni] = *(const bf16x8*)&Bs[0][ni * 16 + lr][k0 + lg * 8];
            bl[ni] = *(const bf16x8*)&Bs[1][ni * 16 + lr][k0 + lg * 8];
        }
#pragma unroll
        for (int mi = 0; mi < 2; mi++)
#pragma unroll
            for (int ni = 0; ni < 3; ni++) {
                acc[mi][ni] = __builtin_amdgcn_mfma_f32_16x16x32_bf16(af[mi], bh[ni],
                                                                      acc[mi][ni], 0, 0, 0);
                acc[mi][ni] = __builtin_amdgcn_mfma_f32_16x16x32_bf16(af[mi], bl[ni],
                                                                      acc[mi][ni], 0, 0, 0);
            }
        __syncthreads();
    }

#pragma unroll
    for (int mi = 0; mi < 2; mi++) {
#pragma unroll
        for (int j = 0; j < 4; j++) {
            int row = row0 + w * 32 + mi * 16 + lg * 4 + j;
            if (row >= kN) continue;
            if (!LAST) {
#pragma unroll
                for (int ni = 0; ni < 3; ni++) {
                    int col = ni * 16 + lr;
                    if (col < kFout) {
                        if (FIRST)
                            z[(size_t)row * kFout + col] = acc[mi][ni][j] + bout[col];
                        else
                            z[(size_t)row * kFout + col] += acc[mi][ni][j];
                    }
                }
            } else {
                const float* zp = z + (size_t)row * kFout;
                float v0 = zp[lr] + acc[mi][0][j];
                float v1 = zp[16 + lr] + acc[mi][1][j];
                float v2 = (lr < 8) ? (zp[32 + lr] + acc[mi][2][j]) : -1e30f;
                float m = fmaxf(fmaxf(v0, v1), v2);
                m = fmaxf(m, __shfl_xor(m, 1, 64));
                m = fmaxf(m, __shfl_xor(m, 2, 64));
                m = fmaxf(m, __shfl_xor(m, 4, 64));
                m = fmaxf(m, __shfl_xor(m, 8, 64));
                float s = expf(v0 - m) + expf(v1 - m) + ((lr < 8) ? expf(v2 - m) : 0.f);
                s += __shfl_xor(s, 1, 64);
                s += __shfl_xor(s, 2, 64);
                s += __shfl_xor(s, 4, 64);
                s += __shfl_xor(s, 8, 64);
                float ls = m + logf(s);
                float* op = out + (size_t)row * kFout;
                op[lr] = v0 - ls;
                op[16 + lr] = v1 - ls;
                if (lr < 8) op[32 + lr] = v2 - ls;
            }
        }
    }
}

extern "C" void kernel_launch(void* const* d_in, const int* in_sizes, int n_in,
                              void* d_out, int out_size, void* d_ws, size_t ws_size,
                              hipStream_t stream) {
    (void)in_sizes; (void)n_in; (void)out_size; (void)ws_size;
    const float* x = (const float*)d_in[0];
    const int* eb = (const int*)d_in[1];
    const float* W_in = (const float*)d_in[2];
    const float* b_in = (const float*)d_in[3];
    const float* W_hid = (const float*)d_in[4];
    const float* b_hid = (const float*)d_in[5];
    const float* gamma = (const float*)d_in[6];
    const float* beta = (const float*)d_in[7];
    const float* W_out = (const float*)d_in[8];
    const float* b_out = (const float*)d_in[9];
    float* out = (float*)d_out;

    char* p = (char*)d_ws;
    auto alloc = [&](size_t b) -> void* {
        void* r = (void*)p;
        p += (b + 255) & ~(size_t)255;
        return r;
    };
    int* flag = (int*)alloc(8);
    int* counts = (int*)alloc((size_t)kN * 4);
    int* off = (int*)alloc((size_t)kN * 4);
    float* dinv = (float*)alloc((size_t)kN * 4);
    float* invdeg = (float*)alloc((size_t)kN * 4);
    float* bnsums = (float*)alloc((size_t)kL * 512 * 4);
    float* bnss = (float*)alloc((size_t)kL * 512 * 4);
    int* rank = (int*)alloc((size_t)kE * 4);
    int* csr_src = (int*)alloc((size_t)kE * 4);
    float* csr_w = (float*)alloc((size_t)kE * 4);
    unsigned short* hA = (unsigned short*)alloc((size_t)kN * kFh * 2);
    unsigned short* hB = (unsigned short*)alloc((size_t)kN * kFh * 2);
    float* z = (float*)alloc((size_t)kN * kFout * 4);
    unsigned short* Wt0 = (unsigned short*)alloc((size_t)kFin * kFh * 2);
    unsigned short* Wt1 = (unsigned short*)alloc((size_t)kFh * kFh * 2);
    unsigned short* Wt2 = (unsigned short*)alloc((size_t)kFh * kFh * 2);
    unsigned short* Wt3 = (unsigned short*)alloc((size_t)kFh * kFh * 2);
    unsigned short* Wto = (unsigned short*)alloc((size_t)kL * 2 * 48 * 256 * 2);

    jk6_zero_i<<<(kN + 255) / 256, 256, 0, stream>>>(counts, kN);
    jk6_zero_f<<<(kL * 512 + 255) / 256, 256, 0, stream>>>(bnsums, kL * 512);
    jk6_detect<<<1, 256, 0, stream>>>(eb, flag);
    jk6_count<<<(kE + 255) / 256, 256, 0, stream>>>(eb, flag, counts, rank);
    jk6_nodeprep<<<(kN + 255) / 256, 256, 0, stream>>>(counts, dinv, invdeg, off, flag + 1);
    jk6_fill<<<(kE + 255) / 256, 256, 0, stream>>>(eb, flag, rank, off, dinv, csr_src, csr_w);

    jk6_wt<<<(kFin * kFh + 255) / 256, 256, 0, stream>>>(W_in, Wt0, kFin);
    jk6_wt<<<(kFh * kFh + 255) / 256, 256, 0, stream>>>(W_hid, Wt1, kFh);
    jk6_wt<<<(kFh * kFh + 255) / 256, 256, 0, stream>>>(W_hid + (size_t)kFh * kFh, Wt2, kFh);
    jk6_wt<<<(kFh * kFh + 255) / 256, 256, 0, stream>>>(W_hid + (size_t)2 * kFh * kFh, Wt3, kFh);
    jk6_wtout<<<(kL * 48 * 256 + 255) / 256, 256, 0, stream>>>(W_out, Wto);

    unsigned short* Wts[4] = {Wt0, Wt1, Wt2, Wt3};
    dim3 gg((kN + 127) / 128, 2);
    int zg = (kN + 127) / 128;
    for (int l = 0; l < kL; l++) {
        const float* b = (l == 0) ? b_in : b_hid + (size_t)(l - 1) * kFh;
        int K = (l == 0) ? kFin : kFh;
        if (l == 0)
            jk6_gemm<1><<<gg, 256, 0, stream>>>(x, Wts[l], hA, K);
        else
            jk6_gemm<0><<<gg, 256, 0, stream>>>(hB, Wts[l], hA, K);
        jk6_agg<<<(kN + 3) / 4, 256, 0, stream>>>(hA, b, off, counts, csr_src, csr_w, invdeg, hB);
        jk6_bnstats<<<1024, 256, 0, stream>>>(hB, bnsums + (size_t)l * 512);
        jk6_bnfinal<<<1, 256, 0, stream>>>(bnsums + (size_t)l * 512, gamma, beta, l,
                                           bnss + (size_t)l * 512, bnss + (size_t)l * 512 + 256);
        const unsigned short* wtl = Wto + (size_t)l * 2 * 48 * 256;
        float* sc = bnss + (size_t)l * 512;
        if (l == 0)
            jk6_zacc<1, 0><<<zg, 256, 0, stream>>>(hB, sc, sc + 256, wtl, b_out, z, out);
        else if (l < kL - 1)
            jk6_zacc<0, 0><<<zg, 256, 0, stream>>>(hB, sc, sc + 256, wtl, b_out, z, out);
        else
            jk6_zacc<0, 1><<<zg, 256, 0, stream>>>(hB, sc, sc + 256, wtl, b_out, z, out);
    }
}

// Round 8
// 1759.282 us; speedup vs baseline: 1.9818x; 1.0244x over previous
//
#include <hip/hip_runtime.h>
#include <math.h>

constexpr int kN = 170000;
constexpr int kE = 2720000;
constexpr int kFin = 128;
constexpr int kFh = 256;
constexpr int kL = 4;
constexpr int kFout = 40;

typedef __attribute__((ext_vector_type(8))) short bf16x8;
typedef __attribute__((ext_vector_type(4))) float f32x4;

__device__ __forceinline__ float jk_b2f(unsigned short u) {
    unsigned int x = ((unsigned int)u) << 16;
    float f;
    __builtin_memcpy(&f, &x, 4);
    return f;
}
__device__ __forceinline__ unsigned short jk_f2b(float f) {
    unsigned int x;
    __builtin_memcpy(&x, &f, 4);
    unsigned int r = (x + 0x7fffu + ((x >> 16) & 1u)) >> 16;
    return (unsigned short)r;
}

union U4 {
    uint4 v;
    unsigned short s[8];
};

__global__ void jk7_zero_i(int* p, int n) {
    int i = blockIdx.x * blockDim.x + threadIdx.x;
    if (i < n) p[i] = 0;
}
__global__ void jk7_zero_f(float* p, int n) {
    int i = blockIdx.x * blockDim.x + threadIdx.x;
    if (i < n) p[i] = 0.0f;
}

// flag[0] = 1 if edge buffer is int64 (element stride shift), else 0; flag[1]=0 cursor.
__global__ void jk7_detect(const int* eb, int* flag) {
    __shared__ int nz;
    if (threadIdx.x == 0) nz = 0;
    __syncthreads();
    int bad = 0;
    for (int j = 0; j < 4; j++) {
        int idx = threadIdx.x * 4 + j;
        if (eb[2 * idx + 1] != 0) bad = 1;
    }
    if (bad) atomicOr(&nz, 1);
    __syncthreads();
    if (threadIdx.x == 0) {
        flag[0] = nz ? 0 : 1;
        flag[1] = 0;
    }
}

// counts[d]++ and remember each edge's rank within its dst bucket.
__global__ void jk7_count(const int* eb, const int* flag, int* counts, int* rank) {
    int e = blockIdx.x * blockDim.x + threadIdx.x;
    if (e >= kE) return;
    int s64 = flag[0];
    int d = eb[(kE + e) << s64];
    rank[e] = atomicAdd(&counts[d], 1);
}

__global__ void jk7_nodeprep(const int* counts, float* dinv, float* invdeg, int* off,
                             int* cursor) {
    int n = blockIdx.x * blockDim.x + threadIdx.x;
    if (n < kN) {
        int c = counts[n];
        float deg = (float)c + 1.0f;
        dinv[n] = rsqrtf(deg);
        invdeg[n] = 1.0f / deg;
        off[n] = atomicAdd(cursor, c);
    }
}

// Atomic-free bucket fill: p = off[d] + rank[e]. One 8B scatter (src, w-bits).
__global__ void jk7_fill(const int* eb, const int* flag, const int* rank, const int* off,
                         const float* dinv, int2* csr) {
    int e = blockIdx.x * blockDim.x + threadIdx.x;
    if (e >= kE) return;
    int s64 = flag[0];
    int s = eb[e << s64];
    int d = eb[(kE + e) << s64];
    int p = off[d] + rank[e];
    float w = dinv[s] * dinv[d];
    csr[p] = make_int2(s, __float_as_int(w));
}

// Wt[c][k] = bf16(W[k][c]);  W: [K][256] fp32, Wt: [256][K] bf16
__global__ void jk7_wt(const float* W, unsigned short* Wt, int K) {
    int idx = blockIdx.x * blockDim.x + threadIdx.x;
    if (idx >= K * kFh) return;
    int c = idx / K, k = idx % K;
    Wt[idx] = jk_f2b(W[(size_t)k * kFh + c]);
}

// Wout slice [l] -> transposed hi/lo bf16 pair.
__global__ void jk7_wtout(const float* Wout, unsigned short* Wto) {
    int idx = blockIdx.x * blockDim.x + threadIdx.x;
    if (idx >= kL * 48 * 256) return;
    int l = idx / (48 * 256);
    int rem = idx % (48 * 256);
    int col = rem >> 8, k = rem & 255;
    float wv = (col < kFout) ? Wout[(size_t)(l * kFh + k) * kFout + col] : 0.f;
    unsigned short hi = jk_f2b(wv);
    float res = wv - jk_b2f(hi);
    unsigned short lo = jk_f2b(res);
    Wto[((size_t)(l * 2 + 0) * 48 + col) * 256 + k] = hi;
    Wto[((size_t)(l * 2 + 1) * 48 + col) * 256 + k] = lo;
}

// C[bf16, kN x 256] = A' @ W, W transposed bf16 Wt[256][K].
// MODE 0: A fp32 (layer 0, no BN). MODE 1: A bf16 raw h + inline BN scale/shift + ReLU.
template <int MODE>
__global__ __launch_bounds__(256) void jk7_gemm(const void* Aptr, const unsigned short* Wt,
                                                unsigned short* C, int K, const float* sc,
                                                const float* sh) {
    __shared__ unsigned short As[128][40];
    __shared__ unsigned short Bs[128][40];
    __shared__ float ssc[256], ssh[256];
    int tid = threadIdx.x;
    if (MODE == 1) {
        ssc[tid] = sc[tid];
        ssh[tid] = sh[tid];
    }
    __syncthreads();
    int row0 = blockIdx.x * 128;
    int n0 = blockIdx.y * 128;
    int lane = tid & 63, w = tid >> 6;
    int wm = w >> 1, wn = w & 1;
    int lr = lane & 15, lg = lane >> 4;

    f32x4 acc[4][4];
#pragma unroll
    for (int i = 0; i < 4; i++)
#pragma unroll
        for (int j = 0; j < 4; j++) acc[i][j] = (f32x4){0.f, 0.f, 0.f, 0.f};

    int sr = tid >> 1;
    int skh = (tid & 1) * 16;

    for (int k0 = 0; k0 < K; k0 += 32) {
        {
            int row = row0 + sr;
            if (MODE == 0) {
                const float* A = (const float*)Aptr;
                unsigned short tmp[16];
                if (row < kN) {
                    const float* g = A + (size_t)row * K + k0 + skh;
#pragma unroll
                    for (int j = 0; j < 16; j++) tmp[j] = jk_f2b(g[j]);
                } else {
#pragma unroll
                    for (int j = 0; j < 16; j++) tmp[j] = 0;
                }
                *(uint4*)&As[sr][skh] = *(uint4*)&tmp[0];
                *(uint4*)&As[sr][skh + 8] = *(uint4*)&tmp[8];
            } else {
                const unsigned short* A = (const unsigned short*)Aptr;
                U4 o0, o1;
                if (row < kN) {
                    U4 u0, u1;
                    const unsigned short* g = A + (size_t)row * K + k0 + skh;
                    u0.v = *(const uint4*)g;
                    u1.v = *(const uint4*)(g + 8);
#pragma unroll
                    for (int j = 0; j < 8; j++) {
                        float v = jk_b2f(u0.s[j]) * ssc[k0 + skh + j] + ssh[k0 + skh + j];
                        o0.s[j] = jk_f2b(v > 0.f ? v : 0.f);
                    }
#pragma unroll
                    for (int j = 0; j < 8; j++) {
                        float v = jk_b2f(u1.s[j]) * ssc[k0 + skh + 8 + j] + ssh[k0 + skh + 8 + j];
                        o1.s[j] = jk_f2b(v > 0.f ? v : 0.f);
                    }
                } else {
#pragma unroll
                    for (int j = 0; j < 8; j++) { o0.s[j] = 0; o1.s[j] = 0; }
                }
                *(uint4*)&As[sr][skh] = o0.v;
                *(uint4*)&As[sr][skh + 8] = o1.v;
            }
        }
        {
            const unsigned short* g = Wt + (size_t)(n0 + sr) * K + k0 + skh;
            *(uint4*)&Bs[sr][skh] = *(const uint4*)g;
            *(uint4*)&Bs[sr][skh + 8] = *(const uint4*)(g + 8);
        }
        __syncthreads();

        bf16x8 af[4], bfr[4];
#pragma unroll
        for (int mi = 0; mi < 4; mi++)
            af[mi] = *(const bf16x8*)&As[wm * 64 + mi * 16 + lr][lg * 8];
#pragma unroll
        for (int ni = 0; ni < 4; ni++)
            bfr[ni] = *(const bf16x8*)&Bs[wn * 64 + ni * 16 + lr][lg * 8];
#pragma unroll
        for (int mi = 0; mi < 4; mi++)
#pragma unroll
            for (int ni = 0; ni < 4; ni++)
                acc[mi][ni] = __builtin_amdgcn_mfma_f32_16x16x32_bf16(af[mi], bfr[ni],
                                                                      acc[mi][ni], 0, 0, 0);
        __syncthreads();
    }

#pragma unroll
    for (int mi = 0; mi < 4; mi++) {
#pragma unroll
        for (int j = 0; j < 4; j++) {
            int row = row0 + wm * 64 + mi * 16 + lg * 4 + j;
            if (row < kN) {
#pragma unroll
                for (int ni = 0; ni < 4; ni++) {
                    int col = n0 + wn * 64 + ni * 16 + lr;
                    C[(size_t)row * kFh + col] = jk_f2b(acc[mi][ni][j]);
                }
            }
        }
    }
}

// h[n,:] = sum_e w_e * t[src_e,:] + t[n,:]*invdeg[n] + bias.
// One node per 32-lane half-wave (8 nodes/block); lane covers 8 channels;
// 4 edges in flight per node; csr = interleaved (src, weight) int2.
__global__ __launch_bounds__(256) void jk7_agg(const unsigned short* t, const float* bias,
                                               const int* off, const int* cnt, const int2* csr,
                                               const float* invdeg, unsigned short* h) {
    int n = blockIdx.x * 8 + (threadIdx.x >> 5);
    if (n >= kN) return;
    int c0 = (threadIdx.x & 31) * 8;

    float acc[8];
    {
        U4 u;
        u.v = *(const uint4*)(t + (size_t)n * kFh + c0);
        float sw = invdeg[n];
#pragma unroll
        for (int j = 0; j < 8; j++) acc[j] = sw * jk_b2f(u.s[j]);
    }

    int base = off[n], c = cnt[n];
    for (int i = 0; i < c; i += 4) {
        float w[4];
        U4 uu[4];
#pragma unroll
        for (int q = 0; q < 4; q++) {
            int e = i + q;
            bool v = e < c;
            int2 cw = csr[v ? base + e : base];
            w[q] = v ? __int_as_float(cw.y) : 0.0f;
            uu[q].v = *(const uint4*)(t + (size_t)cw.x * kFh + c0);
        }
#pragma unroll
        for (int q = 0; q < 4; q++)
#pragma unroll
            for (int j = 0; j < 8; j++) acc[j] += w[q] * jk_b2f(uu[q].s[j]);
    }

    U4 o;
#pragma unroll
    for (int j = 0; j < 8; j++) o.s[j] = jk_f2b(acc[j] + bias[c0 + j]);
    *(uint4*)(h + (size_t)n * kFh + c0) = o.v;
}

// Column sums/sumsq of raw h -> stats[0..255]=sum, [256..511]=sumsq.
__global__ __launch_bounds__(256) void jk7_bnstats(const unsigned short* h, float* stats) {
    __shared__ float lsum[256], lsq[256];
    int tid = threadIdx.x;
    lsum[tid] = 0.f;
    lsq[tid] = 0.f;
    __syncthreads();
    int c0 = (tid & 31) * 8;
    int grp = tid >> 5;
    float rs[8] = {}, rq[8] = {};
    for (int n = blockIdx.x * 8 + grp; n < kN; n += gridDim.x * 8) {
        U4 u;
        u.v = *(const uint4*)(h + (size_t)n * kFh + c0);
#pragma unroll
        for (int j = 0; j < 8; j++) {
            float v = jk_b2f(u.s[j]);
            rs[j] += v;
            rq[j] += v * v;
        }
    }
#pragma unroll
    for (int j = 0; j < 8; j++) {
        atomicAdd(&lsum[c0 + j], rs[j]);
        atomicAdd(&lsq[c0 + j], rq[j]);
    }
    __syncthreads();
    atomicAdd(&stats[tid], lsum[tid]);
    atomicAdd(&stats[256 + tid], lsq[tid]);
}

__global__ void jk7_bnfinal(const float* stats, const float* gamma, const float* beta, int layer,
                            float* scale, float* shift) {
    int c = threadIdx.x;
    float mean = stats[c] / (float)kN;
    float var = stats[256 + c] / (float)kN - mean * mean;
    var = var < 0.f ? 0.f : var;
    float sc = gamma[layer * kFh + c] * rsqrtf(var + 1e-5f);
    scale[c] = sc;
    shift[c] = beta[layer * kFh + c] - mean * sc;
}

// MFMA zacc: reads RAW h, normalizes+ReLU during staging (no write-back),
// z += h_norm @ WoutSlice (hi/lo bf16). LAST fuses log-softmax -> out.
template <int FIRST, int LAST>
__global__ __launch_bounds__(256) void jk7_zacc(const unsigned short* h, const float* scale,
                                                const float* shift, const unsigned short* Wto,
                                                const float* bout, float* z, float* out) {
    __shared__ unsigned short Bs[2][48][264];
    __shared__ unsigned short As[128][40];
    __shared__ float ssc[256], ssh[256];
    int tid = threadIdx.x;
    for (int f = tid; f < 2 * 48 * 256; f += 256) {
        int hl = f / (48 * 256);
        int rem = f % (48 * 256);
        Bs[hl][rem >> 8][rem & 255] = Wto[f];
    }
    ssc[tid] = scale[tid];
    ssh[tid] = shift[tid];
    __syncthreads();

    int row0 = blockIdx.x * 128;
    int w = tid >> 6, lane = tid & 63;
    int lr = lane & 15, lg = lane >> 4;
    int sr = tid >> 1, skh = (tid & 1) * 16;

    f32x4 acc[2][3];
#pragma unroll
    for (int mi = 0; mi < 2; mi++)
#pragma unroll
        for (int ni = 0; ni < 3; ni++) acc[mi][ni] = (f32x4){0.f, 0.f, 0.f, 0.f};

    for (int k0 = 0; k0 < kFh; k0 += 32) {
        int row = row0 + sr;
        U4 o0, o1;
        if (row < kN) {
            U4 u0, u1;
            const unsigned short* g = h + (size_t)row * kFh + k0 + skh;
            u0.v = *(const uint4*)g;
            u1.v = *(const uint4*)(g + 8);
#pragma unroll
            for (int j = 0; j < 8; j++) {
                float v = jk_b2f(u0.s[j]) * ssc[k0 + skh + j] + ssh[k0 + skh + j];
                o0.s[j] = jk_f2b(v > 0.f ? v : 0.f);
            }
#pragma unroll
            for (int j = 0; j < 8; j++) {
                float v = jk_b2f(u1.s[j]) * ssc[k0 + skh + 8 + j] + ssh[k0 + skh + 8 + j];
                o1.s[j] = jk_f2b(v > 0.f ? v : 0.f);
            }
        } else {
#pragma unroll
            for (int j = 0; j < 8; j++) { o0.s[j] = 0; o1.s[j] = 0; }
        }
        *(uint4*)&As[sr][skh] = o0.v;
        *(uint4*)&As[sr][skh + 8] = o1.v;
        __syncthreads();

        bf16x8 af[2], bh[3], bl[3];
#pragma unroll
        for (int mi = 0; mi < 2; mi++)
            af[mi] = *(const bf16x8*)&As[w * 32 + mi * 16 + lr][lg * 8];
#pragma unroll
        for (int ni = 0; ni < 3; ni++) {
            bh[ni] = *(const bf16x8*)&Bs[0][ni * 16 + lr][k0 + lg * 8];
            bl[ni] = *(const bf16x8*)&Bs[1][ni * 16 + lr][k0 + lg * 8];
        }
#pragma unroll
        for (int mi = 0; mi < 2; mi++)
#pragma unroll
            for (int ni = 0; ni < 3; ni++) {
                acc[mi][ni] = __builtin_amdgcn_mfma_f32_16x16x32_bf16(af[mi], bh[ni],
                                                                      acc[mi][ni], 0, 0, 0);
                acc[mi][ni] = __builtin_amdgcn_mfma_f32_16x16x32_bf16(af[mi], bl[ni],
                                                                      acc[mi][ni], 0, 0, 0);
            }
        __syncthreads();
    }

#pragma unroll
    for (int mi = 0; mi < 2; mi++) {
#pragma unroll
        for (int j = 0; j < 4; j++) {
            int row = row0 + w * 32 + mi * 16 + lg * 4 + j;
            if (row >= kN) continue;
            if (!LAST) {
#pragma unroll
                for (int ni = 0; ni < 3; ni++) {
                    int col = ni * 16 + lr;
                    if (col < kFout) {
                        if (FIRST)
                            z[(size_t)row * kFout + col] = acc[mi][ni][j] + bout[col];
                        else
                            z[(size_t)row * kFout + col] += acc[mi][ni][j];
                    }
                }
            } else {
                const float* zp = z + (size_t)row * kFout;
                float v0 = zp[lr] + acc[mi][0][j];
                float v1 = zp[16 + lr] + acc[mi][1][j];
                float v2 = (lr < 8) ? (zp[32 + lr] + acc[mi][2][j]) : -1e30f;
                float m = fmaxf(fmaxf(v0, v1), v2);
                m = fmaxf(m, __shfl_xor(m, 1, 64));
                m = fmaxf(m, __shfl_xor(m, 2, 64));
                m = fmaxf(m, __shfl_xor(m, 4, 64));
                m = fmaxf(m, __shfl_xor(m, 8, 64));
                float s = expf(v0 - m) + expf(v1 - m) + ((lr < 8) ? expf(v2 - m) : 0.f);
                s += __shfl_xor(s, 1, 64);
                s += __shfl_xor(s, 2, 64);
                s += __shfl_xor(s, 4, 64);
                s += __shfl_xor(s, 8, 64);
                float ls = m + logf(s);
                float* op = out + (size_t)row * kFout;
                op[lr] = v0 - ls;
                op[16 + lr] = v1 - ls;
                if (lr < 8) op[32 + lr] = v2 - ls;
            }
        }
    }
}

extern "C" void kernel_launch(void* const* d_in, const int* in_sizes, int n_in,
                              void* d_out, int out_size, void* d_ws, size_t ws_size,
                              hipStream_t stream) {
    (void)in_sizes; (void)n_in; (void)out_size; (void)ws_size;
    const float* x = (const float*)d_in[0];
    const int* eb = (const int*)d_in[1];
    const float* W_in = (const float*)d_in[2];
    const float* b_in = (const float*)d_in[3];
    const float* W_hid = (const float*)d_in[4];
    const float* b_hid = (const float*)d_in[5];
    const float* gamma = (const float*)d_in[6];
    const float* beta = (const float*)d_in[7];
    const float* W_out = (const float*)d_in[8];
    const float* b_out = (const float*)d_in[9];
    float* out = (float*)d_out;

    char* p = (char*)d_ws;
    auto alloc = [&](size_t b) -> void* {
        void* r = (void*)p;
        p += (b + 255) & ~(size_t)255;
        return r;
    };
    int* flag = (int*)alloc(8);
    int* counts = (int*)alloc((size_t)kN * 4);
    int* off = (int*)alloc((size_t)kN * 4);
    float* dinv = (float*)alloc((size_t)kN * 4);
    float* invdeg = (float*)alloc((size_t)kN * 4);
    float* bnsums = (float*)alloc((size_t)kL * 512 * 4);
    float* bnss = (float*)alloc((size_t)kL * 512 * 4);
    int* rank = (int*)alloc((size_t)kE * 4);
    int2* csr = (int2*)alloc((size_t)kE * 8);
    unsigned short* hA = (unsigned short*)alloc((size_t)kN * kFh * 2);
    unsigned short* hB = (unsigned short*)alloc((size_t)kN * kFh * 2);
    float* z = (float*)alloc((size_t)kN * kFout * 4);
    unsigned short* Wt0 = (unsigned short*)alloc((size_t)kFin * kFh * 2);
    unsigned short* Wt1 = (unsigned short*)alloc((size_t)kFh * kFh * 2);
    unsigned short* Wt2 = (unsigned short*)alloc((size_t)kFh * kFh * 2);
    unsigned short* Wt3 = (unsigned short*)alloc((size_t)kFh * kFh * 2);
    unsigned short* Wto = (unsigned short*)alloc((size_t)kL * 2 * 48 * 256 * 2);

    jk7_zero_i<<<(kN + 255) / 256, 256, 0, stream>>>(counts, kN);
    jk7_zero_f<<<(kL * 512 + 255) / 256, 256, 0, stream>>>(bnsums, kL * 512);
    jk7_detect<<<1, 256, 0, stream>>>(eb, flag);
    jk7_count<<<(kE + 255) / 256, 256, 0, stream>>>(eb, flag, counts, rank);
    jk7_nodeprep<<<(kN + 255) / 256, 256, 0, stream>>>(counts, dinv, invdeg, off, flag + 1);
    jk7_fill<<<(kE + 255) / 256, 256, 0, stream>>>(eb, flag, rank, off, dinv, csr);

    jk7_wt<<<(kFin * kFh + 255) / 256, 256, 0, stream>>>(W_in, Wt0, kFin);
    jk7_wt<<<(kFh * kFh + 255) / 256, 256, 0, stream>>>(W_hid, Wt1, kFh);
    jk7_wt<<<(kFh * kFh + 255) / 256, 256, 0, stream>>>(W_hid + (size_t)kFh * kFh, Wt2, kFh);
    jk7_wt<<<(kFh * kFh + 255) / 256, 256, 0, stream>>>(W_hid + (size_t)2 * kFh * kFh, Wt3, kFh);
    jk7_wtout<<<(kL * 48 * 256 + 255) / 256, 256, 0, stream>>>(W_out, Wto);

    unsigned short* Wts[4] = {Wt0, Wt1, Wt2, Wt3};
    dim3 gg((kN + 127) / 128, 2);
    int zg = (kN + 127) / 128;
    for (int l = 0; l < kL; l++) {
        const float* b = (l == 0) ? b_in : b_hid + (size_t)(l - 1) * kFh;
        int K = (l == 0) ? kFin : kFh;
        if (l == 0) {
            jk7_gemm<0><<<gg, 256, 0, stream>>>(x, Wts[l], hA, K, nullptr, nullptr);
        } else {
            float* scp = bnss + (size_t)(l - 1) * 512;
            jk7_gemm<1><<<gg, 256, 0, stream>>>(hB, Wts[l], hA, K, scp, scp + 256);
        }
        jk7_agg<<<(kN + 7) / 8, 256, 0, stream>>>(hA, b, off, counts, csr, invdeg, hB);
        jk7_bnstats<<<1024, 256, 0, stream>>>(hB, bnsums + (size_t)l * 512);
        jk7_bnfinal<<<1, 256, 0, stream>>>(bnsums + (size_t)l * 512, gamma, beta, l,
                                           bnss + (size_t)l * 512, bnss + (size_t)l * 512 + 256);
        const unsigned short* wtl = Wto + (size_t)l * 2 * 48 * 256;
        float* sc = bnss + (size_t)l * 512;
        if (l == 0)
            jk7_zacc<1, 0><<<zg, 256, 0, stream>>>(hB, sc, sc + 256, wtl, b_out, z, out);
        else if (l < kL - 1)
            jk7_zacc<0, 0><<<zg, 256, 0, stream>>>(hB, sc, sc + 256, wtl, b_out, z, out);
        else
            jk7_zacc<0, 1><<<zg, 256, 0, stream>>>(hB, sc, sc + 256, wtl, b_out, z, out);
    }
}

// Round 9
// 1656.108 us; speedup vs baseline: 2.1053x; 1.0623x over previous
//
#include <hip/hip_runtime.h>
#include <math.h>

constexpr int kN = 170000;
constexpr int kE = 2720000;
constexpr int kFin = 128;
constexpr int kFh = 256;
constexpr int kL = 4;
constexpr int kFout = 40;

typedef __attribute__((ext_vector_type(8))) short bf16x8;
typedef __attribute__((ext_vector_type(4))) float f32x4;

__device__ __forceinline__ float jk_b2f(unsigned short u) {
    unsigned int x = ((unsigned int)u) << 16;
    float f;
    __builtin_memcpy(&f, &x, 4);
    return f;
}
__device__ __forceinline__ unsigned short jk_f2b(float f) {
    unsigned int x;
    __builtin_memcpy(&x, &f, 4);
    unsigned int r = (x + 0x7fffu + ((x >> 16) & 1u)) >> 16;
    return (unsigned short)r;
}

union U4 {
    uint4 v;
    unsigned short s[8];
};
union U2 {
    uint2 v;
    unsigned short s[4];
};

__global__ void jk8_zero_i(int* p, int n) {
    int i = blockIdx.x * blockDim.x + threadIdx.x;
    if (i < n) p[i] = 0;
}
__global__ void jk8_zero_f(float* p, int n) {
    int i = blockIdx.x * blockDim.x + threadIdx.x;
    if (i < n) p[i] = 0.0f;
}

// flag[0] = 1 if edge buffer is int64 (element stride shift), else 0; flag[1]=0 cursor.
__global__ void jk8_detect(const int* eb, int* flag) {
    __shared__ int nz;
    if (threadIdx.x == 0) nz = 0;
    __syncthreads();
    int bad = 0;
    for (int j = 0; j < 4; j++) {
        int idx = threadIdx.x * 4 + j;
        if (eb[2 * idx + 1] != 0) bad = 1;
    }
    if (bad) atomicOr(&nz, 1);
    __syncthreads();
    if (threadIdx.x == 0) {
        flag[0] = nz ? 0 : 1;
        flag[1] = 0;
    }
}

// 4 edges/thread: counts[d]++ and record each edge's bucket rank. kE % 4 == 0.
__global__ void jk8_count(const int* eb, const int* flag, int* counts, int* rank) {
    int e0 = (blockIdx.x * blockDim.x + threadIdx.x) * 4;
    if (e0 >= kE) return;
    int s64 = flag[0];
    int d[4];
    if (s64) {
        int4 c1 = *(const int4*)(eb + 2 * ((size_t)kE + e0));
        int4 c2 = *(const int4*)(eb + 2 * ((size_t)kE + e0) + 4);
        d[0] = c1.x; d[1] = c1.z; d[2] = c2.x; d[3] = c2.z;
    } else {
        int4 c1 = *(const int4*)(eb + (size_t)kE + e0);
        d[0] = c1.x; d[1] = c1.y; d[2] = c1.z; d[3] = c1.w;
    }
    int r[4];
#pragma unroll
    for (int q = 0; q < 4; q++) r[q] = atomicAdd(&counts[d[q]], 1);
    *(int4*)(rank + e0) = make_int4(r[0], r[1], r[2], r[3]);
}

__global__ void jk8_nodeprep(const int* counts, float* dinv, float* invdeg, int* off,
                             int* cursor) {
    int n = blockIdx.x * blockDim.x + threadIdx.x;
    if (n < kN) {
        int c = counts[n];
        float deg = (float)c + 1.0f;
        dinv[n] = rsqrtf(deg);
        invdeg[n] = 1.0f / deg;
        off[n] = atomicAdd(cursor, c);
    }
}

// Atomic-free bucket fill, 4 edges/thread: p = off[d] + rank[e]; 8B scatter (src, w).
__global__ void jk8_fill(const int* eb, const int* flag, const int* rank, const int* off,
                         const float* dinv, int2* csr) {
    int e0 = (blockIdx.x * blockDim.x + threadIdx.x) * 4;
    if (e0 >= kE) return;
    int s64 = flag[0];
    int s[4], d[4];
    if (s64) {
        int4 a1 = *(const int4*)(eb + 2 * (size_t)e0);
        int4 a2 = *(const int4*)(eb + 2 * (size_t)e0 + 4);
        s[0] = a1.x; s[1] = a1.z; s[2] = a2.x; s[3] = a2.z;
        int4 c1 = *(const int4*)(eb + 2 * ((size_t)kE + e0));
        int4 c2 = *(const int4*)(eb + 2 * ((size_t)kE + e0) + 4);
        d[0] = c1.x; d[1] = c1.z; d[2] = c2.x; d[3] = c2.z;
    } else {
        int4 a1 = *(const int4*)(eb + (size_t)e0);
        s[0] = a1.x; s[1] = a1.y; s[2] = a1.z; s[3] = a1.w;
        int4 c1 = *(const int4*)(eb + (size_t)kE + e0);
        d[0] = c1.x; d[1] = c1.y; d[2] = c1.z; d[3] = c1.w;
    }
    int4 rr = *(const int4*)(rank + e0);
    int r[4] = {rr.x, rr.y, rr.z, rr.w};
#pragma unroll
    for (int q = 0; q < 4; q++) {
        int p = off[d[q]] + r[q];
        float w = dinv[s[q]] * dinv[d[q]];
        csr[p] = make_int2(s[q], __float_as_int(w));
    }
}

// Single weight-prep kernel: Wt0 (128xK transpose), Wt1..3 (256x256 transposes,
// contiguous in Wt1), Wto (hi/lo bf16 Wout slices). 278528 threads total.
__global__ void jk8_prepw(const float* W_in, const float* W_hid, const float* Wout,
                          unsigned short* Wt0, unsigned short* Wt1, unsigned short* Wto) {
    int idx = blockIdx.x * blockDim.x + threadIdx.x;
    if (idx < 32768) {
        int c = idx >> 7, k = idx & 127;
        Wt0[idx] = jk_f2b(W_in[(size_t)k * kFh + c]);
    } else if (idx < 32768 + 196608) {
        int t2 = idx - 32768;
        int l = t2 >> 16, rem = t2 & 65535;
        int c = rem >> 8, k = rem & 255;
        Wt1[(size_t)l * 65536 + rem] = jk_f2b(W_hid[(size_t)l * 65536 + k * kFh + c]);
    } else if (idx < 32768 + 196608 + 49152) {
        int t2 = idx - 32768 - 196608;
        int l = t2 / (48 * 256), rem = t2 % (48 * 256);
        int col = rem >> 8, k = rem & 255;
        float wv = (col < kFout) ? Wout[(size_t)(l * kFh + k) * kFout + col] : 0.f;
        unsigned short hi = jk_f2b(wv);
        unsigned short lo = jk_f2b(wv - jk_b2f(hi));
        Wto[((size_t)(l * 2 + 0) * 48 + col) * 256 + k] = hi;
        Wto[((size_t)(l * 2 + 1) * 48 + col) * 256 + k] = lo;
    }
}

// x f32 [kN][128] -> bf16, 8 elems/thread.
__global__ void jk8_xb(const float* x, unsigned short* xb) {
    int i = blockIdx.x * blockDim.x + threadIdx.x;
    if (i >= kN * kFin / 8) return;
    float4 a = *(const float4*)(x + (size_t)i * 8);
    float4 b = *(const float4*)(x + (size_t)i * 8 + 4);
    U4 o;
    o.s[0] = jk_f2b(a.x); o.s[1] = jk_f2b(a.y); o.s[2] = jk_f2b(a.z); o.s[3] = jk_f2b(a.w);
    o.s[4] = jk_f2b(b.x); o.s[5] = jk_f2b(b.y); o.s[6] = jk_f2b(b.z); o.s[7] = jk_f2b(b.w);
    *(uint4*)(xb + (size_t)i * 8) = o.v;
}

// C[bf16, kN x 256] = A' @ W, W transposed bf16 Wt[256][K].
// MODE 0: A bf16 plain (K=128), epilogue adds bias[col].
// MODE 1: A bf16 raw h with inline BN scale/shift + ReLU (K=256), no bias.
template <int MODE>
__global__ __launch_bounds__(256) void jk8_gemm(const unsigned short* A, const unsigned short* Wt,
                                                unsigned short* C, int K, const float* sc,
                                                const float* sh, const float* bias) {
    __shared__ unsigned short As[128][40];
    __shared__ unsigned short Bs[128][40];
    __shared__ float ssc[256], ssh[256];
    int tid = threadIdx.x;
    if (MODE == 1) {
        ssc[tid] = sc[tid];
        ssh[tid] = sh[tid];
    } else {
        ssc[tid] = bias[tid];
    }
    __syncthreads();
    int row0 = blockIdx.x * 128;
    int n0 = blockIdx.y * 128;
    int lane = tid & 63, w = tid >> 6;
    int wm = w >> 1, wn = w & 1;
    int lr = lane & 15, lg = lane >> 4;

    f32x4 acc[4][4];
#pragma unroll
    for (int i = 0; i < 4; i++)
#pragma unroll
        for (int j = 0; j < 4; j++) acc[i][j] = (f32x4){0.f, 0.f, 0.f, 0.f};

    int sr = tid >> 1;
    int skh = (tid & 1) * 16;

    for (int k0 = 0; k0 < K; k0 += 32) {
        {
            int row = row0 + sr;
            if (MODE == 0) {
                uint4 u0 = make_uint4(0, 0, 0, 0), u1 = make_uint4(0, 0, 0, 0);
                if (row < kN) {
                    const unsigned short* g = A + (size_t)row * K + k0 + skh;
                    u0 = *(const uint4*)g;
                    u1 = *(const uint4*)(g + 8);
                }
                *(uint4*)&As[sr][skh] = u0;
                *(uint4*)&As[sr][skh + 8] = u1;
            } else {
                U4 o0, o1;
                if (row < kN) {
                    U4 u0, u1;
                    const unsigned short* g = A + (size_t)row * K + k0 + skh;
                    u0.v = *(const uint4*)g;
                    u1.v = *(const uint4*)(g + 8);
#pragma unroll
                    for (int j = 0; j < 8; j++) {
                        float v = jk_b2f(u0.s[j]) * ssc[k0 + skh + j] + ssh[k0 + skh + j];
                        o0.s[j] = jk_f2b(v > 0.f ? v : 0.f);
                    }
#pragma unroll
                    for (int j = 0; j < 8; j++) {
                        float v = jk_b2f(u1.s[j]) * ssc[k0 + skh + 8 + j] + ssh[k0 + skh + 8 + j];
                        o1.s[j] = jk_f2b(v > 0.f ? v : 0.f);
                    }
                } else {
#pragma unroll
                    for (int j = 0; j < 8; j++) { o0.s[j] = 0; o1.s[j] = 0; }
                }
                *(uint4*)&As[sr][skh] = o0.v;
                *(uint4*)&As[sr][skh + 8] = o1.v;
            }
        }
        {
            const unsigned short* g = Wt + (size_t)(n0 + sr) * K + k0 + skh;
            *(uint4*)&Bs[sr][skh] = *(const uint4*)g;
            *(uint4*)&Bs[sr][skh + 8] = *(const uint4*)(g + 8);
        }
        __syncthreads();

        bf16x8 af[4], bfr[4];
#pragma unroll
        for (int mi = 0; mi < 4; mi++)
            af[mi] = *(const bf16x8*)&As[wm * 64 + mi * 16 + lr][lg * 8];
#pragma unroll
        for (int ni = 0; ni < 4; ni++)
            bfr[ni] = *(const bf16x8*)&Bs[wn * 64 + ni * 16 + lr][lg * 8];
#pragma unroll
        for (int mi = 0; mi < 4; mi++)
#pragma unroll
            for (int ni = 0; ni < 4; ni++)
                acc[mi][ni] = __builtin_amdgcn_mfma_f32_16x16x32_bf16(af[mi], bfr[ni],
                                                                      acc[mi][ni], 0, 0, 0);
        __syncthreads();
    }

#pragma unroll
    for (int mi = 0; mi < 4; mi++) {
#pragma unroll
        for (int j = 0; j < 4; j++) {
            int row = row0 + wm * 64 + mi * 16 + lg * 4 + j;
            if (row < kN) {
#pragma unroll
                for (int ni = 0; ni < 4; ni++) {
                    int col = n0 + wn * 64 + ni * 16 + lr;
                    float v = acc[mi][ni][j];
                    if (MODE == 0) v += ssc[col];
                    C[(size_t)row * kFh + col] = jk_f2b(v);
                }
            }
        }
    }
}

// h[n,:] = sum_e w_e * t[src_e,:] + t[n,:]*invdeg[n] (+ bias).
// One node per 32-lane group; CH=128: lane=4ch (uint2), depth 8; CH=256: lane=8ch, depth 6.
template <int CH, int HASB>
__global__ __launch_bounds__(256) void jk8_agg(const unsigned short* t, const float* bias,
                                               const int* off, const int* cnt, const int2* csr,
                                               const float* invdeg, unsigned short* h) {
    constexpr int PC = CH / 32;
    constexpr int DEPTH = (CH == 128) ? 8 : 6;
    int n = blockIdx.x * 8 + (threadIdx.x >> 5);
    if (n >= kN) return;
    int c0 = (threadIdx.x & 31) * PC;

    float acc[PC];
    {
        float sw = invdeg[n];
        if constexpr (PC == 8) {
            U4 u;
            u.v = *(const uint4*)(t + (size_t)n * CH + c0);
#pragma unroll
            for (int j = 0; j < 8; j++) acc[j] = sw * jk_b2f(u.s[j]);
        } else {
            U2 u;
            u.v = *(const uint2*)(t + (size_t)n * CH + c0);
#pragma unroll
            for (int j = 0; j < 4; j++) acc[j] = sw * jk_b2f(u.s[j]);
        }
    }

    int base = off[n], c = cnt[n];
    for (int i = 0; i < c; i += DEPTH) {
        float w[DEPTH];
        U4 u8[PC == 8 ? DEPTH : 1];
        U2 u4[PC == 4 ? DEPTH : 1];
#pragma unroll
        for (int q = 0; q < DEPTH; q++) {
            int e = i + q;
            bool v = e < c;
            int2 cw = csr[v ? base + e : base];
            w[q] = v ? __int_as_float(cw.y) : 0.0f;
            if constexpr (PC == 8)
                u8[q].v = *(const uint4*)(t + (size_t)cw.x * CH + c0);
            else
                u4[q].v = *(const uint2*)(t + (size_t)cw.x * CH + c0);
        }
#pragma unroll
        for (int q = 0; q < DEPTH; q++) {
            if constexpr (PC == 8) {
#pragma unroll
                for (int j = 0; j < 8; j++) acc[j] += w[q] * jk_b2f(u8[q].s[j]);
            } else {
#pragma unroll
                for (int j = 0; j < 4; j++) acc[j] += w[q] * jk_b2f(u4[q].s[j]);
            }
        }
    }

    if constexpr (PC == 8) {
        U4 o;
#pragma unroll
        for (int j = 0; j < 8; j++)
            o.s[j] = jk_f2b(HASB ? acc[j] + bias[c0 + j] : acc[j]);
        *(uint4*)(h + (size_t)n * CH + c0) = o.v;
    } else {
        U2 o;
#pragma unroll
        for (int j = 0; j < 4; j++)
            o.s[j] = jk_f2b(HASB ? acc[j] + bias[c0 + j] : acc[j]);
        *(uint2*)(h + (size_t)n * CH + c0) = o.v;
    }
}

// Column sums/sumsq of raw h -> stats[0..255]=sum, [256..511]=sumsq.
__global__ __launch_bounds__(256) void jk8_bnstats(const unsigned short* h, float* stats) {
    __shared__ float lsum[256], lsq[256];
    int tid = threadIdx.x;
    lsum[tid] = 0.f;
    lsq[tid] = 0.f;
    __syncthreads();
    int c0 = (tid & 31) * 8;
    int grp = tid >> 5;
    float rs[8] = {}, rq[8] = {};
    for (int n = blockIdx.x * 8 + grp; n < kN; n += gridDim.x * 8) {
        U4 u;
        u.v = *(const uint4*)(h + (size_t)n * kFh + c0);
#pragma unroll
        for (int j = 0; j < 8; j++) {
            float v = jk_b2f(u.s[j]);
            rs[j] += v;
            rq[j] += v * v;
        }
    }
#pragma unroll
    for (int j = 0; j < 8; j++) {
        atomicAdd(&lsum[c0 + j], rs[j]);
        atomicAdd(&lsq[c0 + j], rq[j]);
    }
    __syncthreads();
    atomicAdd(&stats[tid], lsum[tid]);
    atomicAdd(&stats[256 + tid], lsq[tid]);
}

__global__ void jk8_bnfinal(const float* stats, const float* gamma, const float* beta, int layer,
                            float* scale, float* shift) {
    int c = threadIdx.x;
    float mean = stats[c] / (float)kN;
    float var = stats[256 + c] / (float)kN - mean * mean;
    var = var < 0.f ? 0.f : var;
    float sc = gamma[layer * kFh + c] * rsqrtf(var + 1e-5f);
    scale[c] = sc;
    shift[c] = beta[layer * kFh + c] - mean * sc;
}

// MFMA zacc: reads RAW h, normalizes+ReLU during staging (no write-back),
// z += h_norm @ WoutSlice (hi/lo bf16). LAST fuses log-softmax -> out.
template <int FIRST, int LAST>
__global__ __launch_bounds__(256) void jk8_zacc(const unsigned short* h, const float* scale,
                                                const float* shift, const unsigned short* Wto,
                                                const float* bout, float* z, float* out) {
    __shared__ unsigned short Bs[2][48][264];
    __shared__ unsigned short As[128][40];
    __shared__ float ssc[256], ssh[256];
    int tid = threadIdx.x;
    for (int f = tid; f < 2 * 48 * 256; f += 256) {
        int hl = f / (48 * 256);
        int rem = f % (48 * 256);
        Bs[hl][rem >> 8][rem & 255] = Wto[f];
    }
    ssc[tid] = scale[tid];
    ssh[tid] = shift[tid];
    __syncthreads();

    int row0 = blockIdx.x * 128;
    int w = tid >> 6, lane = tid & 63;
    int lr = lane & 15, lg = lane >> 4;
    int sr = tid >> 1, skh = (tid & 1) * 16;

    f32x4 acc[2][3];
#pragma unroll
    for (int mi = 0; mi < 2; mi++)
#pragma unroll
        for (int ni = 0; ni < 3; ni++) acc[mi][ni] = (f32x4){0.f, 0.f, 0.f, 0.f};

    for (int k0 = 0; k0 < kFh; k0 += 32) {
        int row = row0 + sr;
        U4 o0, o1;
        if (row < kN) {
            U4 u0, u1;
            const unsigned short* g = h + (size_t)row * kFh + k0 + skh;
            u0.v = *(const uint4*)g;
            u1.v = *(const uint4*)(g + 8);
#pragma unroll
            for (int j = 0; j < 8; j++) {
                float v = jk_b2f(u0.s[j]) * ssc[k0 + skh + j] + ssh[k0 + skh + j];
                o0.s[j] = jk_f2b(v > 0.f ? v : 0.f);
            }
#pragma unroll
            for (int j = 0; j < 8; j++) {
                float v = jk_b2f(u1.s[j]) * ssc[k0 + skh + 8 + j] + ssh[k0 + skh + 8 + j];
                o1.s[j] = jk_f2b(v > 0.f ? v : 0.f);
            }
        } else {
#pragma unroll
            for (int j = 0; j < 8; j++) { o0.s[j] = 0; o1.s[j] = 0; }
        }
        *(uint4*)&As[sr][skh] = o0.v;
        *(uint4*)&As[sr][skh + 8] = o1.v;
        __syncthreads();

        bf16x8 af[2], bh[3], bl[3];
#pragma unroll
        for (int mi = 0; mi < 2; mi++)
            af[mi] = *(const bf16x8*)&As[w * 32 + mi * 16 + lr][lg * 8];
#pragma unroll
        for (int ni = 0; ni < 3; ni++) {
            bh[ni] = *(const bf16x8*)&Bs[0][ni * 16 + lr][k0 + lg * 8];
            bl[ni] = *(const bf16x8*)&Bs[1][ni * 16 + lr][k0 + lg * 8];
        }
#pragma unroll
        for (int mi = 0; mi < 2; mi++)
#pragma unroll
            for (int ni = 0; ni < 3; ni++) {
                acc[mi][ni] = __builtin_amdgcn_mfma_f32_16x16x32_bf16(af[mi], bh[ni],
                                                                      acc[mi][ni], 0, 0, 0);
                acc[mi][ni] = __builtin_amdgcn_mfma_f32_16x16x32_bf16(af[mi], bl[ni],
                                                                      acc[mi][ni], 0, 0, 0);
            }
        __syncthreads();
    }

#pragma unroll
    for (int mi = 0; mi < 2; mi++) {
#pragma unroll
        for (int j = 0; j < 4; j++) {
            int row = row0 + w * 32 + mi * 16 + lg * 4 + j;
            if (row >= kN) continue;
            if (!LAST) {
#pragma unroll
                for (int ni = 0; ni < 3; ni++) {
                    int col = ni * 16 + lr;
                    if (col < kFout) {
                        if (FIRST)
                            z[(size_t)row * kFout + col] = acc[mi][ni][j] + bout[col];
                        else
                            z[(size_t)row * kFout + col] += acc[mi][ni][j];
                    }
                }
            } else {
                const float* zp = z + (size_t)row * kFout;
                float v0 = zp[lr] + acc[mi][0][j];
                float v1 = zp[16 + lr] + acc[mi][1][j];
                float v2 = (lr < 8) ? (zp[32 + lr] + acc[mi][2][j]) : -1e30f;
                float m = fmaxf(fmaxf(v0, v1), v2);
                m = fmaxf(m, __shfl_xor(m, 1, 64));
                m = fmaxf(m, __shfl_xor(m, 2, 64));
                m = fmaxf(m, __shfl_xor(m, 4, 64));
                m = fmaxf(m, __shfl_xor(m, 8, 64));
                float s = expf(v0 - m) + expf(v1 - m) + ((lr < 8) ? expf(v2 - m) : 0.f);
                s += __shfl_xor(s, 1, 64);
                s += __shfl_xor(s, 2, 64);
                s += __shfl_xor(s, 4, 64);
                s += __shfl_xor(s, 8, 64);
                float ls = m + logf(s);
                float* op = out + (size_t)row * kFout;
                op[lr] = v0 - ls;
                op[16 + lr] = v1 - ls;
                if (lr < 8) op[32 + lr] = v2 - ls;
            }
        }
    }
}

extern "C" void kernel_launch(void* const* d_in, const int* in_sizes, int n_in,
                              void* d_out, int out_size, void* d_ws, size_t ws_size,
                              hipStream_t stream) {
    (void)in_sizes; (void)n_in; (void)out_size; (void)ws_size;
    const float* x = (const float*)d_in[0];
    const int* eb = (const int*)d_in[1];
    const float* W_in = (const float*)d_in[2];
    const float* b_in = (const float*)d_in[3];
    const float* W_hid = (const float*)d_in[4];
    const float* b_hid = (const float*)d_in[5];
    const float* gamma = (const float*)d_in[6];
    const float* beta = (const float*)d_in[7];
    const float* W_out = (const float*)d_in[8];
    const float* b_out = (const float*)d_in[9];
    float* out = (float*)d_out;

    char* p = (char*)d_ws;
    auto alloc = [&](size_t b) -> void* {
        void* r = (void*)p;
        p += (b + 255) & ~(size_t)255;
        return r;
    };
    int* flag = (int*)alloc(8);
    int* counts = (int*)alloc((size_t)kN * 4);
    int* off = (int*)alloc((size_t)kN * 4);
    float* dinv = (float*)alloc((size_t)kN * 4);
    float* invdeg = (float*)alloc((size_t)kN * 4);
    float* bnsums = (float*)alloc((size_t)kL * 512 * 4);
    float* bnss = (float*)alloc((size_t)kL * 512 * 4);
    int* rank = (int*)alloc((size_t)kE * 4);
    int2* csr = (int2*)alloc((size_t)kE * 8);
    unsigned short* hA = (unsigned short*)alloc((size_t)kN * kFh * 2);
    unsigned short* hB = (unsigned short*)alloc((size_t)kN * kFh * 2);
    float* z = (float*)alloc((size_t)kN * kFout * 4);
    unsigned short* Wt0 = (unsigned short*)alloc((size_t)kFin * kFh * 2);
    unsigned short* Wt1 = (unsigned short*)alloc((size_t)3 * kFh * kFh * 2);
    unsigned short* Wto = (unsigned short*)alloc((size_t)kL * 2 * 48 * 256 * 2);

    jk8_zero_i<<<(kN + 255) / 256, 256, 0, stream>>>(counts, kN);
    jk8_zero_f<<<(kL * 512 + 255) / 256, 256, 0, stream>>>(bnsums, kL * 512);
    jk8_detect<<<1, 256, 0, stream>>>(eb, flag);
    jk8_count<<<(kE / 4 + 255) / 256, 256, 0, stream>>>(eb, flag, counts, rank);
    jk8_nodeprep<<<(kN + 255) / 256, 256, 0, stream>>>(counts, dinv, invdeg, off, flag + 1);
    jk8_fill<<<(kE / 4 + 255) / 256, 256, 0, stream>>>(eb, flag, rank, off, dinv, csr);
    jk8_prepw<<<(32768 + 196608 + 49152 + 255) / 256, 256, 0, stream>>>(W_in, W_hid, W_out,
                                                                        Wt0, Wt1, Wto);
    // layer 0: aggregate-first (Agg(x) @ W == Agg(x @ W)); xb lives in hB, Agg(x) in hA.
    jk8_xb<<<(kN * kFin / 8 + 255) / 256, 256, 0, stream>>>(x, hB);
    jk8_agg<128, 0><<<(kN + 7) / 8, 256, 0, stream>>>(hB, nullptr, off, counts, csr, invdeg, hA);

    unsigned short* Wts[4] = {Wt0, Wt1, Wt1 + 65536, Wt1 + 131072};
    dim3 gg((kN + 127) / 128, 2);
    int zg = (kN + 127) / 128;
    for (int l = 0; l < kL; l++) {
        if (l == 0) {
            jk8_gemm<0><<<gg, 256, 0, stream>>>(hA, Wts[0], hB, kFin, nullptr, nullptr, b_in);
        } else {
            const float* b = b_hid + (size_t)(l - 1) * kFh;
            float* scp = bnss + (size_t)(l - 1) * 512;
            jk8_gemm<1><<<gg, 256, 0, stream>>>(hB, Wts[l], hA, kFh, scp, scp + 256, nullptr);
            jk8_agg<256, 1><<<(kN + 7) / 8, 256, 0, stream>>>(hA, b, off, counts, csr, invdeg,
                                                              hB);
        }
        jk8_bnstats<<<1024, 256, 0, stream>>>(hB, bnsums + (size_t)l * 512);
        jk8_bnfinal<<<1, 256, 0, stream>>>(bnsums + (size_t)l * 512, gamma, beta, l,
                                           bnss + (size_t)l * 512, bnss + (size_t)l * 512 + 256);
        const unsigned short* wtl = Wto + (size_t)l * 2 * 48 * 256;
        float* sc = bnss + (size_t)l * 512;
        if (l == 0)
            jk8_zacc<1, 0><<<zg, 256, 0, stream>>>(hB, sc, sc + 256, wtl, b_out, z, out);
        else if (l < kL - 1)
            jk8_zacc<0, 0><<<zg, 256, 0, stream>>>(hB, sc, sc + 256, wtl, b_out, z, out);
        else
            jk8_zacc<0, 1><<<zg, 256, 0, stream>>>(hB, sc, sc + 256, wtl, b_out, z, out);
    }
}